// Round 5
// baseline (1180.382 us; speedup 1.0000x reference)
//
#include <hip/hip_runtime.h>
#include <math.h>

#define N_NODES   20000
#define N_EDGES   160000
#define N_LEDGES  1280000
#define N_TOTE    (N_LEDGES + N_EDGES)   // edges incl. self-loops
#define IN_FEAT   128
#define HIDDEN    64
#define FEAT      128
#define OUT_FEAT  16
#define NUM_LAYERS 8
#define ALPHA     0.1f
#define CHUNK     4

typedef __attribute__((ext_vector_type(4))) float f32x4;
typedef __attribute__((ext_vector_type(8))) short bf16x8;

__device__ __forceinline__ float2 bf2(uint u) {
  union { uint i; float f; } a, b;
  a.i = u << 16;
  b.i = u & 0xffff0000u;
  float2 r; r.x = a.f; r.y = b.f; return r;
}
__device__ __forceinline__ ushort f2bf(float f) {
  union { float f; uint i; } u; u.f = f;
  uint r = u.i + 0x7fffu + ((u.i >> 16) & 1u);
  return (ushort)(r >> 16);
}
__device__ __forceinline__ uint pack2(float x, float y) {
  return (uint)f2bf(x) | ((uint)f2bf(y) << 16);
}

// ---------------- lin0 + relu ----------------
__global__ __launch_bounds__(256) void k_lin0(const float* __restrict__ x,
                                              const float* __restrict__ w,
                                              const float* __restrict__ b,
                                              float* __restrict__ h) {
  int node = blockIdx.x * 4 + (threadIdx.x >> 6);
  int j = threadIdx.x & 63;
  if (node >= N_NODES) return;
  const float* xr = x + (size_t)node * IN_FEAT;
  float acc = b[j];
  #pragma unroll
  for (int k = 0; k < IN_FEAT; k++) acc = fmaf(xr[k], w[k * HIDDEN + j], acc);
  h[(size_t)node * HIDDEN + j] = fmaxf(acc, 0.f);
}

// ---------------- e[i] = [h[src]||h[dst]] (bf16); x0 = e ----------------
__global__ __launch_bounds__(256) void k_build_e(const int* __restrict__ src,
                                                 const int* __restrict__ dst,
                                                 const float* __restrict__ h,
                                                 ushort* __restrict__ e,
                                                 ushort* __restrict__ x0) {
  int gid = blockIdx.x * 256 + threadIdx.x;
  int edge = gid >> 5;
  int p = gid & 31;
  if (edge >= N_EDGES) return;
  int n = (p < 16) ? src[edge] : dst[edge];
  float4 v = ((const float4*)(h + (size_t)n * HIDDEN))[p & 15];
  uint2 pk;
  pk.x = pack2(v.x, v.y);
  pk.y = pack2(v.z, v.w);
  ((uint2*)(e  + ((size_t)edge << 7)))[p] = pk;
  ((uint2*)(x0 + ((size_t)edge << 7)))[p] = pk;
}

// ---------------- init: deg=0, cnt=1 (self-loop pre-counted) ----------------
__global__ __launch_bounds__(256) void k_init(int* __restrict__ deg,
                                              int* __restrict__ cnt) {
  int i = blockIdx.x * 256 + threadIdx.x;
  if (i < N_EDGES) { deg[i] = 0; cnt[i] = 1; }
}

// ---------------- degree over col, count over row (4 edges/thread) ----------------
__global__ __launch_bounds__(256) void k_count(const int4* __restrict__ lrow4,
                                               const int4* __restrict__ lcol4,
                                               int* __restrict__ deg,
                                               int* __restrict__ cnt) {
  int k = blockIdx.x * 256 + threadIdx.x;
  if (k >= N_LEDGES / 4) return;
  int4 r = lrow4[k], c = lcol4[k];
  atomicAdd(&deg[c.x], 1); atomicAdd(&deg[c.y], 1);
  atomicAdd(&deg[c.z], 1); atomicAdd(&deg[c.w], 1);
  atomicAdd(&cnt[r.x], 1); atomicAdd(&cnt[r.y], 1);
  atomicAdd(&cnt[r.z], 1); atomicAdd(&cnt[r.w], 1);
}

__global__ __launch_bounds__(256) void k_dis(const int* __restrict__ deg,
                                             float* __restrict__ dis) {
  int i = blockIdx.x * 256 + threadIdx.x;
  if (i < N_EDGES) dis[i] = rsqrtf((float)(deg[i] + 1));  // +1 self-loop
}

// ---------------- exclusive scan of cnt -> row_ptr ----------------
__global__ __launch_bounds__(256) void k_scanA(const int* __restrict__ cnt,
                                               int* __restrict__ out,
                                               int* __restrict__ bsum) {
  __shared__ int sh[256];
  int tid = threadIdx.x;
  int base = blockIdx.x * 1024 + tid * 4;
  int v[4];
  #pragma unroll
  for (int i = 0; i < 4; i++) v[i] = (base + i < N_EDGES) ? cnt[base + i] : 0;
  int t = v[0] + v[1] + v[2] + v[3];
  sh[tid] = t;
  __syncthreads();
  for (int off = 1; off < 256; off <<= 1) {
    int xv = (tid >= off) ? sh[tid - off] : 0;
    __syncthreads();
    sh[tid] += xv;
    __syncthreads();
  }
  int run = sh[tid] - t;
  #pragma unroll
  for (int i = 0; i < 4; i++) {
    if (base + i < N_EDGES) out[base + i] = run;
    run += v[i];
  }
  if (tid == 255) bsum[blockIdx.x] = sh[255];
}

__global__ void k_scanB(int* __restrict__ bsum, int nb) {
  __shared__ int sh[256];
  int tid = threadIdx.x;
  int v = (tid < nb) ? bsum[tid] : 0;
  sh[tid] = v;
  __syncthreads();
  for (int off = 1; off < 256; off <<= 1) {
    int xv = (tid >= off) ? sh[tid - off] : 0;
    __syncthreads();
    sh[tid] += xv;
    __syncthreads();
  }
  if (tid < nb) bsum[tid] = sh[tid] - v;  // exclusive
}

__global__ __launch_bounds__(256) void k_scanC(int* __restrict__ row_ptr,
                                               const int* __restrict__ bsum) {
  int tid = threadIdx.x;
  int base = blockIdx.x * 1024 + tid * 4;
  int add = bsum[blockIdx.x];
  #pragma unroll
  for (int i = 0; i < 4; i++)
    if (base + i < N_EDGES) row_ptr[base + i] += add;
  if (blockIdx.x == 0 && tid == 0) row_ptr[N_EDGES] = N_TOTE;
}

// ---------------- fill CSR: pv[pos] = {col, 0.9*val} ----------------
__global__ __launch_bounds__(256) void k_fill(const int* __restrict__ lrow,
                                              const int* __restrict__ lcol,
                                              const int* __restrict__ row_ptr,
                                              int* __restrict__ cnt,
                                              const float* __restrict__ dis,
                                              uint2* __restrict__ pv) {
  int k = blockIdx.x * 256 + threadIdx.x;
  if (k >= N_LEDGES) return;
  int r = lrow[k], c = lcol[k];
  int pos = row_ptr[r] + atomicSub(&cnt[r], 1) - 1;
  uint2 out;
  out.x = (uint)c;
  out.y = __float_as_uint((1.f - ALPHA) * dis[r] * dis[c]);
  pv[pos] = out;
}

// self-loop edges: pv entry {r, 0.9*dis[r]^2}
__global__ __launch_bounds__(256) void k_fill_self(const int* __restrict__ row_ptr,
                                                   int* __restrict__ cnt,
                                                   const float* __restrict__ dis,
                                                   uint2* __restrict__ pv) {
  int r = blockIdx.x * 256 + threadIdx.x;
  if (r >= N_EDGES) return;
  int pos = row_ptr[r] + atomicSub(&cnt[r], 1) - 1;
  float d = dis[r];
  uint2 out;
  out.x = (uint)r;
  out.y = __float_as_uint((1.f - ALPHA) * d * d);
  pv[pos] = out;
}

// ---------------- Bt[c][k] = bf16(beta*W[k][c] + (k==c)*(1-beta)); Bt2 = 0.1*Bt ----------------
__global__ __launch_bounds__(256) void k_prepw(const float* __restrict__ W,
                                               ushort* __restrict__ Bt,
                                               ushort* __restrict__ Bt2) {
  int gid = blockIdx.x * 256 + threadIdx.x;
  if (gid >= NUM_LAYERS * FEAT * FEAT) return;
  int l = gid >> 14;
  int rem = gid & 16383;
  int k = rem >> 7, c = rem & 127;
  float beta = logf(0.5f / (float)(l + 1) + 1.0f);
  float v = beta * W[gid];
  if (k == c) v += 1.0f - beta;
  int o = (l << 14) + (c << 7) + k;
  Bt[o]  = f2bf(v);
  Bt2[o] = f2bf(ALPHA * v);
}

// ---------------- W1f[c][k] = bf16(W1[k][c]) ----------------
__global__ __launch_bounds__(256) void k_prepw1(const float* __restrict__ W1,
                                                ushort* __restrict__ W1f) {
  int gid = blockIdx.x * 256 + threadIdx.x;
  if (gid >= FEAT * OUT_FEAT) return;
  int k = gid >> 4, c = gid & 15;
  W1f[c * FEAT + k] = f2bf(W1[gid]);
}

// ---------------- gather phase (shared by both layer kernels) ----------------
__device__ __forceinline__ void gather_phase(const int* __restrict__ row_ptr,
                                             const uint2* __restrict__ pv,
                                             const uint* __restrict__ eu,
                                             ushort* As, int row0, int wv, int lane) {
  int r0w = row0 + wv * 16;
  int rpidx = r0w + lane;
  if (rpidx > N_EDGES) rpidx = N_EDGES;
  int myrp = row_ptr[rpidx];

  int t    = __builtin_amdgcn_readfirstlane(__shfl(myrp, 0));
  int tend = __builtin_amdgcn_readfirstlane(__shfl(myrp, 16));
  int r    = r0w;
  int end  = __builtin_amdgcn_readfirstlane(__shfl(myrp, 1));

  float ax = 0.f, ay = 0.f;

  uint cA[CHUNK], uA[CHUNK]; float vA[CHUNK];
  uint cB[CHUNK], uB[CHUNK]; float vB[CHUNK];

  auto loadpv = [&](int tb_, uint* cc, float* vv) {
    #pragma unroll
    for (int j = 0; j < CHUNK; j++) {
      int tj = tb_ + j;
      uint2 p = pv[tj];                       // padded array: unguarded load
      bool valid = (tj < tend);
      cc[j] = valid ? p.x : (uint)0;
      vv[j] = valid ? __uint_as_float(p.y) : 0.f;
    }
  };
  auto gather = [&](const uint* cc, uint* uu) {
    #pragma unroll
    for (int j = 0; j < CHUNK; j++) {
      int cu = __builtin_amdgcn_readfirstlane((int)cc[j]);
      uu[j] = eu[((size_t)cu << 6) + lane];
    }
  };
  auto flush = [&]() {
    int rl = r - row0;
    *(uint*)((char*)As + rl * 256 + ((lane * 4) ^ ((rl & 7) << 4))) = pack2(ax, ay);
    ax = 0.f; ay = 0.f;
  };
  auto consume = [&](int tb_, const uint* cc, const float* vv, const uint* uu) {
    #pragma unroll
    for (int j = 0; j < CHUNK; j++) {
      int tj = tb_ + j;
      if (tj < tend) {
        while (tj >= end) {                    // row boundary (wave-uniform)
          flush();
          r++;
          end = __builtin_amdgcn_readfirstlane(__shfl(myrp, r - r0w + 1));
        }
        float2 f = bf2(uu[j]);
        ax = fmaf(vv[j], f.x, ax);
        ay = fmaf(vv[j], f.y, ay);
      }
    }
  };

  int tb = t;
  loadpv(tb, cA, vA); gather(cA, uA);
  while (true) {
    if (tb + CHUNK < tend) { loadpv(tb + CHUNK, cB, vB); gather(cB, uB); }
    consume(tb, cA, vA, uA);
    tb += CHUNK;
    if (tb >= tend) break;
    if (tb + CHUNK < tend) { loadpv(tb + CHUNK, cA, vA); gather(cA, uA); }
    consume(tb, cB, vB, uB);
    tb += CHUNK;
    if (tb >= tend) break;
  }
  flush();  // last row (every row has >=1 edge via self-loop)
}

// ---------------- MFMA accumulate: acc = As@W' + x0tile@W2 ----------------
__device__ __forceinline__ void mfma_accum(const ushort* As,
                                           const ushort* __restrict__ x0,
                                           const ushort* __restrict__ Bt,
                                           const ushort* __restrict__ Bt2,
                                           int row0, int wv, int l15, int l4,
                                           f32x4 acc[4][2]) {
  const char* btA  = (const char*)Bt  + (size_t)(wv * 32 + l15) * 256;
  const char* btB  = btA + 16 * 256;
  const char* bt2A = (const char*)Bt2 + (size_t)(wv * 32 + l15) * 256;
  const char* bt2B = bt2A + 16 * 256;
  const char* x0b  = (const char*)x0 + ((size_t)row0 << 8);
  #pragma unroll
  for (int kb = 0; kb < 4; kb++) {
    int kbyte = kb * 64 + l4 * 16;
    bf16x8 b0 = *(const bf16x8*)(btA + kbyte);
    bf16x8 b1 = *(const bf16x8*)(btB + kbyte);
    bf16x8 q0 = *(const bf16x8*)(bt2A + kbyte);
    bf16x8 q1 = *(const bf16x8*)(bt2B + kbyte);
    #pragma unroll
    for (int mr = 0; mr < 4; mr++) {
      int rr = mr * 16 + l15;
      bf16x8 afr = *(const bf16x8*)((const char*)As + rr * 256 + (kbyte ^ ((rr & 7) << 4)));
      bf16x8 xfr = *(const bf16x8*)(x0b + (size_t)rr * 256 + kbyte);
      acc[mr][0] = __builtin_amdgcn_mfma_f32_16x16x32_bf16(afr, b0, acc[mr][0], 0, 0, 0);
      acc[mr][1] = __builtin_amdgcn_mfma_f32_16x16x32_bf16(afr, b1, acc[mr][1], 0, 0, 0);
      acc[mr][0] = __builtin_amdgcn_mfma_f32_16x16x32_bf16(xfr, q0, acc[mr][0], 0, 0, 0);
      acc[mr][1] = __builtin_amdgcn_mfma_f32_16x16x32_bf16(xfr, q1, acc[mr][1], 0, 0, 0);
    }
  }
}

// ---------------- fused layer (layers 0..6): -> e_out bf16 ----------------
__global__ __launch_bounds__(256, 8) void k_layer(const int* __restrict__ row_ptr,
                                                  const uint2* __restrict__ pv,
                                                  const ushort* __restrict__ e_in,
                                                  const ushort* __restrict__ x0,
                                                  const ushort* __restrict__ Bt,
                                                  const ushort* __restrict__ Bt2,
                                                  ushort* __restrict__ e_out) {
  __shared__ __align__(16) ushort As[64 * 128];  // 16KB
  int tid = threadIdx.x;
  int wv = tid >> 6, lane = tid & 63;
  int l15 = lane & 15, l4 = lane >> 4;
  int row0 = blockIdx.x * 64;

  gather_phase(row_ptr, pv, (const uint*)e_in, As, row0, wv, lane);
  __syncthreads();

  f32x4 acc[4][2];
  #pragma unroll
  for (int i = 0; i < 4; i++) { acc[i][0] = (f32x4)0; acc[i][1] = (f32x4)0; }
  mfma_accum(As, x0, Bt, Bt2, row0, wv, l15, l4, acc);

  #pragma unroll
  for (int mr = 0; mr < 4; mr++) {
    #pragma unroll
    for (int n = 0; n < 2; n++) {
      int col = wv * 32 + n * 16 + l15;
      int rowb = row0 + mr * 16 + l4 * 4;
      #pragma unroll
      for (int j = 0; j < 4; j++) {
        float v = fmaxf(acc[mr][n][j], 0.f);
        e_out[((size_t)(rowb + j) << 7) + col] = f2bf(v);
      }
    }
  }
}

// ---------------- last layer: fused lin1, writes out fp32 ----------------
__global__ __launch_bounds__(256, 4) void k_layer_last(const int* __restrict__ row_ptr,
                                                       const uint2* __restrict__ pv,
                                                       const ushort* __restrict__ e_in,
                                                       const ushort* __restrict__ x0,
                                                       const ushort* __restrict__ Bt,
                                                       const ushort* __restrict__ Bt2,
                                                       const ushort* __restrict__ W1f,
                                                       const float* __restrict__ b1,
                                                       float* __restrict__ out) {
  __shared__ __align__(16) ushort As[64 * 128];  // 16KB
  int tid = threadIdx.x;
  int wv = tid >> 6, lane = tid & 63;
  int l15 = lane & 15, l4 = lane >> 4;
  int row0 = blockIdx.x * 64;

  gather_phase(row_ptr, pv, (const uint*)e_in, As, row0, wv, lane);
  __syncthreads();

  f32x4 acc[4][2];
  #pragma unroll
  for (int i = 0; i < 4; i++) { acc[i][0] = (f32x4)0; acc[i][1] = (f32x4)0; }
  mfma_accum(As, x0, Bt, Bt2, row0, wv, l15, l4, acc);

  __syncthreads();  // all waves done reading As
  // relu -> bf16 e-tile back into As (swizzled)
  #pragma unroll
  for (int mr = 0; mr < 4; mr++) {
    #pragma unroll
    for (int n = 0; n < 2; n++) {
      int col = wv * 32 + n * 16 + l15;
      int rowb = mr * 16 + l4 * 4;
      #pragma unroll
      for (int j = 0; j < 4; j++) {
        int rl = rowb + j;
        float v = fmaxf(acc[mr][n][j], 0.f);
        *(ushort*)((char*)As + rl * 256 + ((col * 2) ^ ((rl & 7) << 4))) = f2bf(v);
      }
    }
  }
  __syncthreads();

  // lin1: out(64x16) = e_tile(64x128) @ W1(128x16) + b1
  f32x4 acc2[4];
  #pragma unroll
  for (int i = 0; i < 4; i++) acc2[i] = (f32x4)0;
  const char* w1p = (const char*)W1f + (size_t)l15 * 256;
  #pragma unroll
  for (int kb = 0; kb < 4; kb++) {
    int kbyte = kb * 64 + l4 * 16;
    bf16x8 wfr = *(const bf16x8*)(w1p + kbyte);
    #pragma unroll
    for (int mr = 0; mr < 4; mr++) {
      int rr = mr * 16 + l15;
      bf16x8 afr = *(const bf16x8*)((const char*)As + rr * 256 + (kbyte ^ ((rr & 7) << 4)));
      acc2[mr] = __builtin_amdgcn_mfma_f32_16x16x32_bf16(afr, wfr, acc2[mr], 0, 0, 0);
    }
  }
  float bias = b1[l15];
  #pragma unroll
  for (int mr = 0; mr < 4; mr++) {
    int rowb = row0 + mr * 16 + l4 * 4;
    #pragma unroll
    for (int j = 0; j < 4; j++)
      out[(size_t)(rowb + j) * OUT_FEAT + l15] = acc2[mr][j] + bias;
  }
}

extern "C" void kernel_launch(void* const* d_in, const int* in_sizes, int n_in,
                              void* d_out, int out_size, void* d_ws, size_t ws_size,
                              hipStream_t stream) {
  const float* x   = (const float*)d_in[0];
  const int*   ei  = (const int*)d_in[1];
  const int*   lei = (const int*)d_in[2];
  const float* w0  = (const float*)d_in[3];
  const float* b0  = (const float*)d_in[4];
  const float* cw  = (const float*)d_in[5];
  const float* w1  = (const float*)d_in[6];
  const float* b1  = (const float*)d_in[7];
  float* out = (float*)d_out;

  char* ws = (char*)d_ws;
  size_t off = 0;
  auto alloc = [&](size_t bytes) -> void* {
    void* p = ws + off;
    off += (bytes + 255) & ~(size_t)255;
    return p;
  };
  float*  h      = (float*)alloc((size_t)N_NODES * HIDDEN * 4);
  ushort* x0     = (ushort*)alloc((size_t)N_EDGES * FEAT * 2);
  ushort* eA     = (ushort*)alloc((size_t)N_EDGES * FEAT * 2);
  ushort* eB     = (ushort*)alloc((size_t)N_EDGES * FEAT * 2);
  ushort* Btp    = (ushort*)alloc((size_t)NUM_LAYERS * FEAT * FEAT * 2);
  ushort* Btp2   = (ushort*)alloc((size_t)NUM_LAYERS * FEAT * FEAT * 2);
  ushort* W1f    = (ushort*)alloc((size_t)FEAT * OUT_FEAT * 2);
  int*    deg    = (int*)alloc((size_t)N_EDGES * 4);
  float*  dis    = (float*)alloc((size_t)N_EDGES * 4);
  int*    cnt    = (int*)alloc((size_t)N_EDGES * 4);
  int*    row_ptr= (int*)alloc((size_t)(N_EDGES + 1) * 4);
  uint2*  pv     = (uint2*)alloc(((size_t)N_TOTE + 16) * 8);  // +pad for unguarded loads
  int*    bsum   = (int*)alloc(256 * 4);

  k_lin0<<<(N_NODES + 3) / 4, 256, 0, stream>>>(x, w0, b0, h);
  k_build_e<<<(N_EDGES * 32 + 255) / 256, 256, 0, stream>>>(ei, ei + N_EDGES, h, eA, x0);
  k_init<<<(N_EDGES + 255) / 256, 256, 0, stream>>>(deg, cnt);
  k_count<<<(N_LEDGES / 4 + 255) / 256, 256, 0, stream>>>((const int4*)lei,
                                                          (const int4*)(lei + N_LEDGES), deg, cnt);
  k_dis<<<(N_EDGES + 255) / 256, 256, 0, stream>>>(deg, dis);
  const int nscan = (N_EDGES + 1023) / 1024;  // 157
  k_scanA<<<nscan, 256, 0, stream>>>(cnt, row_ptr, bsum);
  k_scanB<<<1, 256, 0, stream>>>(bsum, nscan);
  k_scanC<<<nscan, 256, 0, stream>>>(row_ptr, bsum);
  k_fill<<<(N_LEDGES + 255) / 256, 256, 0, stream>>>(lei, lei + N_LEDGES, row_ptr, cnt, dis, pv);
  k_fill_self<<<(N_EDGES + 255) / 256, 256, 0, stream>>>(row_ptr, cnt, dis, pv);
  k_prepw<<<(NUM_LAYERS * FEAT * FEAT + 255) / 256, 256, 0, stream>>>(cw, Btp, Btp2);
  k_prepw1<<<(FEAT * OUT_FEAT + 255) / 256, 256, 0, stream>>>(w1, W1f);

  ushort* ein = eA;
  ushort* eout = eB;
  for (int l = 0; l < NUM_LAYERS - 1; l++) {
    k_layer<<<N_EDGES / 64, 256, 0, stream>>>(row_ptr, pv, ein, x0,
                                              Btp + ((size_t)l << 14),
                                              Btp2 + ((size_t)l << 14), eout);
    ushort* t = ein; ein = eout; eout = t;
  }
  k_layer_last<<<N_EDGES / 64, 256, 0, stream>>>(row_ptr, pv, ein, x0,
                                                 Btp + ((size_t)(NUM_LAYERS - 1) << 14),
                                                 Btp2 + ((size_t)(NUM_LAYERS - 1) << 14),
                                                 W1f, b1, out);
}

// Round 6
// 966.273 us; speedup vs baseline: 1.2216x; 1.2216x over previous
//
#include <hip/hip_runtime.h>
#include <math.h>

#define N_NODES   20000
#define N_EDGES   160000
#define N_LEDGES  1280000
#define N_TOTE    (N_LEDGES + N_EDGES)   // edges incl. self-loops
#define IN_FEAT   128
#define HIDDEN    64
#define FEAT      128
#define OUT_FEAT  16
#define NUM_LAYERS 8
#define ALPHA     0.1f
#define CHUNK     8

typedef __attribute__((ext_vector_type(4))) float f32x4;
typedef __attribute__((ext_vector_type(8))) short bf16x8;

__device__ __forceinline__ float2 bf2(uint u) {
  union { uint i; float f; } a, b;
  a.i = u << 16;
  b.i = u & 0xffff0000u;
  float2 r; r.x = a.f; r.y = b.f; return r;
}
__device__ __forceinline__ ushort f2bf(float f) {
  union { float f; uint i; } u; u.f = f;
  uint r = u.i + 0x7fffu + ((u.i >> 16) & 1u);
  return (ushort)(r >> 16);
}
__device__ __forceinline__ uint pack2(float x, float y) {
  return (uint)f2bf(x) | ((uint)f2bf(y) << 16);
}

// ---------------- lin0 + relu ----------------
__global__ __launch_bounds__(256) void k_lin0(const float* __restrict__ x,
                                              const float* __restrict__ w,
                                              const float* __restrict__ b,
                                              float* __restrict__ h) {
  int node = blockIdx.x * 4 + (threadIdx.x >> 6);
  int j = threadIdx.x & 63;
  if (node >= N_NODES) return;
  const float* xr = x + (size_t)node * IN_FEAT;
  float acc = b[j];
  #pragma unroll
  for (int k = 0; k < IN_FEAT; k++) acc = fmaf(xr[k], w[k * HIDDEN + j], acc);
  h[(size_t)node * HIDDEN + j] = fmaxf(acc, 0.f);
}

// ---------------- e[i] = [h[src]||h[dst]] (bf16); x0 = e ----------------
__global__ __launch_bounds__(256) void k_build_e(const int* __restrict__ src,
                                                 const int* __restrict__ dst,
                                                 const float* __restrict__ h,
                                                 ushort* __restrict__ e,
                                                 ushort* __restrict__ x0) {
  int gid = blockIdx.x * 256 + threadIdx.x;
  int edge = gid >> 5;
  int p = gid & 31;
  if (edge >= N_EDGES) return;
  int n = (p < 16) ? src[edge] : dst[edge];
  float4 v = ((const float4*)(h + (size_t)n * HIDDEN))[p & 15];
  uint2 pk;
  pk.x = pack2(v.x, v.y);
  pk.y = pack2(v.z, v.w);
  ((uint2*)(e  + ((size_t)edge << 7)))[p] = pk;
  ((uint2*)(x0 + ((size_t)edge << 7)))[p] = pk;
}

// ---------------- init: deg=0, cnt=1 (self-loop pre-counted) ----------------
__global__ __launch_bounds__(256) void k_init(int* __restrict__ deg,
                                              int* __restrict__ cnt) {
  int i = blockIdx.x * 256 + threadIdx.x;
  if (i < N_EDGES) { deg[i] = 0; cnt[i] = 1; }
}

// ---------------- degree over col, count over row (4 edges/thread) ----------------
__global__ __launch_bounds__(256) void k_count(const int4* __restrict__ lrow4,
                                               const int4* __restrict__ lcol4,
                                               int* __restrict__ deg,
                                               int* __restrict__ cnt) {
  int k = blockIdx.x * 256 + threadIdx.x;
  if (k >= N_LEDGES / 4) return;
  int4 r = lrow4[k], c = lcol4[k];
  atomicAdd(&deg[c.x], 1); atomicAdd(&deg[c.y], 1);
  atomicAdd(&deg[c.z], 1); atomicAdd(&deg[c.w], 1);
  atomicAdd(&cnt[r.x], 1); atomicAdd(&cnt[r.y], 1);
  atomicAdd(&cnt[r.z], 1); atomicAdd(&cnt[r.w], 1);
}

__global__ __launch_bounds__(256) void k_dis(const int* __restrict__ deg,
                                             float* __restrict__ dis) {
  int i = blockIdx.x * 256 + threadIdx.x;
  if (i < N_EDGES) dis[i] = rsqrtf((float)(deg[i] + 1));  // +1 self-loop
}

// ---------------- exclusive scan of cnt -> row_ptr ----------------
__global__ __launch_bounds__(256) void k_scanA(const int* __restrict__ cnt,
                                               int* __restrict__ out,
                                               int* __restrict__ bsum) {
  __shared__ int sh[256];
  int tid = threadIdx.x;
  int base = blockIdx.x * 1024 + tid * 4;
  int v[4];
  #pragma unroll
  for (int i = 0; i < 4; i++) v[i] = (base + i < N_EDGES) ? cnt[base + i] : 0;
  int t = v[0] + v[1] + v[2] + v[3];
  sh[tid] = t;
  __syncthreads();
  for (int off = 1; off < 256; off <<= 1) {
    int xv = (tid >= off) ? sh[tid - off] : 0;
    __syncthreads();
    sh[tid] += xv;
    __syncthreads();
  }
  int run = sh[tid] - t;
  #pragma unroll
  for (int i = 0; i < 4; i++) {
    if (base + i < N_EDGES) out[base + i] = run;
    run += v[i];
  }
  if (tid == 255) bsum[blockIdx.x] = sh[255];
}

__global__ void k_scanB(int* __restrict__ bsum, int nb) {
  __shared__ int sh[256];
  int tid = threadIdx.x;
  int v = (tid < nb) ? bsum[tid] : 0;
  sh[tid] = v;
  __syncthreads();
  for (int off = 1; off < 256; off <<= 1) {
    int xv = (tid >= off) ? sh[tid - off] : 0;
    __syncthreads();
    sh[tid] += xv;
    __syncthreads();
  }
  if (tid < nb) bsum[tid] = sh[tid] - v;  // exclusive
}

__global__ __launch_bounds__(256) void k_scanC(int* __restrict__ row_ptr,
                                               const int* __restrict__ bsum) {
  int tid = threadIdx.x;
  int base = blockIdx.x * 1024 + tid * 4;
  int add = bsum[blockIdx.x];
  #pragma unroll
  for (int i = 0; i < 4; i++)
    if (base + i < N_EDGES) row_ptr[base + i] += add;
  if (blockIdx.x == 0 && tid == 0) row_ptr[N_EDGES] = N_TOTE;
}

// ---------------- fill CSR: pv[pos] = {col, 0.9*val} ----------------
__global__ __launch_bounds__(256) void k_fill(const int* __restrict__ lrow,
                                              const int* __restrict__ lcol,
                                              const int* __restrict__ row_ptr,
                                              int* __restrict__ cnt,
                                              const float* __restrict__ dis,
                                              uint2* __restrict__ pv) {
  int k = blockIdx.x * 256 + threadIdx.x;
  if (k >= N_LEDGES) return;
  int r = lrow[k], c = lcol[k];
  int pos = row_ptr[r] + atomicSub(&cnt[r], 1) - 1;
  uint2 out;
  out.x = (uint)c;
  out.y = __float_as_uint((1.f - ALPHA) * dis[r] * dis[c]);
  pv[pos] = out;
}

// self-loop edges: pv entry {r, 0.9*dis[r]^2}
__global__ __launch_bounds__(256) void k_fill_self(const int* __restrict__ row_ptr,
                                                   int* __restrict__ cnt,
                                                   const float* __restrict__ dis,
                                                   uint2* __restrict__ pv) {
  int r = blockIdx.x * 256 + threadIdx.x;
  if (r >= N_EDGES) return;
  int pos = row_ptr[r] + atomicSub(&cnt[r], 1) - 1;
  float d = dis[r];
  uint2 out;
  out.x = (uint)r;
  out.y = __float_as_uint((1.f - ALPHA) * d * d);
  pv[pos] = out;
}

// ---------------- Bt[c][k] = bf16(beta*W[k][c] + (k==c)*(1-beta)); Bt2 = 0.1*Bt ----------------
__global__ __launch_bounds__(256) void k_prepw(const float* __restrict__ W,
                                               ushort* __restrict__ Bt,
                                               ushort* __restrict__ Bt2) {
  int gid = blockIdx.x * 256 + threadIdx.x;
  if (gid >= NUM_LAYERS * FEAT * FEAT) return;
  int l = gid >> 14;
  int rem = gid & 16383;
  int k = rem >> 7, c = rem & 127;
  float beta = logf(0.5f / (float)(l + 1) + 1.0f);
  float v = beta * W[gid];
  if (k == c) v += 1.0f - beta;
  int o = (l << 14) + (c << 7) + k;
  Bt[o]  = f2bf(v);
  Bt2[o] = f2bf(ALPHA * v);
}

// ---------------- W1f[c][k] = bf16(W1[k][c]) ----------------
__global__ __launch_bounds__(256) void k_prepw1(const float* __restrict__ W1,
                                                ushort* __restrict__ W1f) {
  int gid = blockIdx.x * 256 + threadIdx.x;
  if (gid >= FEAT * OUT_FEAT) return;
  int k = gid >> 4, c = gid & 15;
  W1f[c * FEAT + k] = f2bf(W1[gid]);
}

// ---------------- gather phase: segmented stream, 8 gathers in flight ----------------
// pv loaded 16 entries/line (one coalesced 128B load per 16 edges); entries
// distributed via __shfl; gather base in SGPR (saddr-form global_load).
__device__ __forceinline__ void gather_phase(const int* __restrict__ row_ptr,
                                             const uint2* __restrict__ pv,
                                             const uint* __restrict__ eu,
                                             ushort* As, int row0, int wv, int lane) {
  int r0w = row0 + wv * 16;
  int rpidx = r0w + lane;
  if (rpidx > N_EDGES) rpidx = N_EDGES;
  int myrp = row_ptr[rpidx];

  int t    = __builtin_amdgcn_readfirstlane(__shfl(myrp, 0));
  int tend = __builtin_amdgcn_readfirstlane(__shfl(myrp, 16));
  int r    = r0w;
  int end  = __builtin_amdgcn_readfirstlane(__shfl(myrp, 1));

  float ax = 0.f, ay = 0.f;
  uint uA[CHUNK], uB[CHUNK];
  uint2 P, Pn;

  auto loadpv16 = [&](int tb_, uint2& p) {
    p = pv[tb_ + (lane & 15)];            // 128B line, covers 2 chunks
  };
  auto gather8 = [&](int tb_, const uint2& p, int base, uint* uu) {
    #pragma unroll
    for (int j = 0; j < CHUNK; j++) {
      int cu = (tb_ + j < tend)
                 ? __builtin_amdgcn_readfirstlane(__shfl((int)p.x, base + j))
                 : 0;
      uu[j] = eu[((size_t)cu << 6) + lane];
    }
  };
  auto flush = [&]() {
    int rl = r - row0;
    *(uint*)((char*)As + rl * 256 + ((lane * 4) ^ ((rl & 7) << 4))) = pack2(ax, ay);
    ax = 0.f; ay = 0.f;
  };
  auto consume8 = [&](int tb_, const uint2& p, int base, const uint* uu) {
    #pragma unroll
    for (int j = 0; j < CHUNK; j++) {
      int tj = tb_ + j;
      if (tj < tend) {                      // wave-uniform
        while (tj >= end) {                 // row boundary (wave-uniform)
          flush();
          r++;
          end = __builtin_amdgcn_readfirstlane(__shfl(myrp, r - r0w + 1));
        }
        float v = __uint_as_float(__shfl((int)p.y, base + j));
        float2 f = bf2(uu[j]);
        ax = fmaf(v, f.x, ax);
        ay = fmaf(v, f.y, ay);
      }
    }
  };

  int tb = t;
  loadpv16(tb, P);
  gather8(tb, P, 0, uA);
  while (true) {
    loadpv16(tb + 16, Pn);                  // pv for chunks +2,+3
    gather8(tb + CHUNK, P, 8, uB);
    consume8(tb, P, 0, uA);
    tb += CHUNK;
    if (tb >= tend) break;
    gather8(tb + CHUNK, Pn, 0, uA);
    consume8(tb, P, 8, uB);
    tb += CHUNK;
    if (tb >= tend) break;
    P = Pn;
  }
  flush();  // last row (every row has >=1 edge via self-loop)
}

// ---------------- MFMA accumulate: acc = As@W' + x0tile@W2 ----------------
__device__ __forceinline__ void mfma_accum(const ushort* As,
                                           const ushort* __restrict__ x0,
                                           const ushort* __restrict__ Bt,
                                           const ushort* __restrict__ Bt2,
                                           int row0, int wv, int l15, int l4,
                                           f32x4 acc[4][2]) {
  const char* btA  = (const char*)Bt  + (size_t)(wv * 32 + l15) * 256;
  const char* btB  = btA + 16 * 256;
  const char* bt2A = (const char*)Bt2 + (size_t)(wv * 32 + l15) * 256;
  const char* bt2B = bt2A + 16 * 256;
  const char* x0b  = (const char*)x0 + ((size_t)row0 << 8);
  #pragma unroll
  for (int kb = 0; kb < 4; kb++) {
    int kbyte = kb * 64 + l4 * 16;
    bf16x8 b0 = *(const bf16x8*)(btA + kbyte);
    bf16x8 b1 = *(const bf16x8*)(btB + kbyte);
    bf16x8 q0 = *(const bf16x8*)(bt2A + kbyte);
    bf16x8 q1 = *(const bf16x8*)(bt2B + kbyte);
    #pragma unroll
    for (int mr = 0; mr < 4; mr++) {
      int rr = mr * 16 + l15;
      bf16x8 afr = *(const bf16x8*)((const char*)As + rr * 256 + (kbyte ^ ((rr & 7) << 4)));
      bf16x8 xfr = *(const bf16x8*)(x0b + (size_t)rr * 256 + kbyte);
      acc[mr][0] = __builtin_amdgcn_mfma_f32_16x16x32_bf16(afr, b0, acc[mr][0], 0, 0, 0);
      acc[mr][1] = __builtin_amdgcn_mfma_f32_16x16x32_bf16(afr, b1, acc[mr][1], 0, 0, 0);
      acc[mr][0] = __builtin_amdgcn_mfma_f32_16x16x32_bf16(xfr, q0, acc[mr][0], 0, 0, 0);
      acc[mr][1] = __builtin_amdgcn_mfma_f32_16x16x32_bf16(xfr, q1, acc[mr][1], 0, 0, 0);
    }
  }
}

// ---------------- fused layer (layers 0..6): -> e_out bf16 ----------------
__global__ __launch_bounds__(256, 4) void k_layer(const int* __restrict__ row_ptr,
                                                  const uint2* __restrict__ pv,
                                                  const ushort* __restrict__ e_in,
                                                  const ushort* __restrict__ x0,
                                                  const ushort* __restrict__ Bt,
                                                  const ushort* __restrict__ Bt2,
                                                  ushort* __restrict__ e_out) {
  __shared__ __align__(16) ushort As[64 * 128];  // 16KB
  int tid = threadIdx.x;
  int wv = tid >> 6, lane = tid & 63;
  int l15 = lane & 15, l4 = lane >> 4;
  int row0 = blockIdx.x * 64;

  gather_phase(row_ptr, pv, (const uint*)e_in, As, row0, wv, lane);
  __syncthreads();

  f32x4 acc[4][2];
  #pragma unroll
  for (int i = 0; i < 4; i++) { acc[i][0] = (f32x4)0; acc[i][1] = (f32x4)0; }
  mfma_accum(As, x0, Bt, Bt2, row0, wv, l15, l4, acc);

  __syncthreads();  // all waves done reading As
  // stage relu(acc) into As as [row][col] bf16 (XOR bits 4-6 per row)
  #pragma unroll
  for (int mr = 0; mr < 4; mr++) {
    #pragma unroll
    for (int n = 0; n < 2; n++) {
      int col = wv * 32 + n * 16 + l15;
      #pragma unroll
      for (int j = 0; j < 4; j++) {
        int rl = mr * 16 + l4 * 4 + j;
        float v = fmaxf(acc[mr][n][j], 0.f);
        *(ushort*)((char*)As + rl * 256 + ((col * 2) ^ ((rl & 7) << 4))) = f2bf(v);
      }
    }
  }
  __syncthreads();
  // full-line coalesced copy-out: 1024 16B chunks
  const char* asb = (const char*)As;
  #pragma unroll
  for (int k2 = 0; k2 < 4; k2++) {
    int q = k2 * 256 + tid;
    int rl = q >> 4, ck = q & 15;
    uint4 v = *(const uint4*)(asb + rl * 256 + ((ck * 16) ^ ((rl & 7) << 4)));
    *(uint4*)((char*)e_out + (((size_t)(row0 + rl)) << 8) + ck * 16) = v;
  }
}

// ---------------- last layer: fused lin1, writes out fp32 ----------------
__global__ __launch_bounds__(256, 4) void k_layer_last(const int* __restrict__ row_ptr,
                                                       const uint2* __restrict__ pv,
                                                       const ushort* __restrict__ e_in,
                                                       const ushort* __restrict__ x0,
                                                       const ushort* __restrict__ Bt,
                                                       const ushort* __restrict__ Bt2,
                                                       const ushort* __restrict__ W1f,
                                                       const float* __restrict__ b1,
                                                       float* __restrict__ out) {
  __shared__ __align__(16) ushort As[64 * 128];  // 16KB
  int tid = threadIdx.x;
  int wv = tid >> 6, lane = tid & 63;
  int l15 = lane & 15, l4 = lane >> 4;
  int row0 = blockIdx.x * 64;

  gather_phase(row_ptr, pv, (const uint*)e_in, As, row0, wv, lane);
  __syncthreads();

  f32x4 acc[4][2];
  #pragma unroll
  for (int i = 0; i < 4; i++) { acc[i][0] = (f32x4)0; acc[i][1] = (f32x4)0; }
  mfma_accum(As, x0, Bt, Bt2, row0, wv, l15, l4, acc);

  __syncthreads();  // all waves done reading As
  // relu -> bf16 e-tile back into As (swizzled)
  #pragma unroll
  for (int mr = 0; mr < 4; mr++) {
    #pragma unroll
    for (int n = 0; n < 2; n++) {
      int col = wv * 32 + n * 16 + l15;
      #pragma unroll
      for (int j = 0; j < 4; j++) {
        int rl = mr * 16 + l4 * 4 + j;
        float v = fmaxf(acc[mr][n][j], 0.f);
        *(ushort*)((char*)As + rl * 256 + ((col * 2) ^ ((rl & 7) << 4))) = f2bf(v);
      }
    }
  }
  __syncthreads();

  // lin1: out(64x16) = e_tile(64x128) @ W1(128x16) + b1
  f32x4 acc2[4];
  #pragma unroll
  for (int i = 0; i < 4; i++) acc2[i] = (f32x4)0;
  const char* w1p = (const char*)W1f + (size_t)l15 * 256;
  #pragma unroll
  for (int kb = 0; kb < 4; kb++) {
    int kbyte = kb * 64 + l4 * 16;
    bf16x8 wfr = *(const bf16x8*)(w1p + kbyte);
    #pragma unroll
    for (int mr = 0; mr < 4; mr++) {
      int rr = mr * 16 + l15;
      bf16x8 afr = *(const bf16x8*)((const char*)As + rr * 256 + (kbyte ^ ((rr & 7) << 4)));
      acc2[mr] = __builtin_amdgcn_mfma_f32_16x16x32_bf16(afr, wfr, acc2[mr], 0, 0, 0);
    }
  }
  float bias = b1[l15];
  #pragma unroll
  for (int mr = 0; mr < 4; mr++) {
    int rowb = row0 + mr * 16 + l4 * 4;
    #pragma unroll
    for (int j = 0; j < 4; j++)
      out[(size_t)(rowb + j) * OUT_FEAT + l15] = acc2[mr][j] + bias;
  }
}

extern "C" void kernel_launch(void* const* d_in, const int* in_sizes, int n_in,
                              void* d_out, int out_size, void* d_ws, size_t ws_size,
                              hipStream_t stream) {
  const float* x   = (const float*)d_in[0];
  const int*   ei  = (const int*)d_in[1];
  const int*   lei = (const int*)d_in[2];
  const float* w0  = (const float*)d_in[3];
  const float* b0  = (const float*)d_in[4];
  const float* cw  = (const float*)d_in[5];
  const float* w1  = (const float*)d_in[6];
  const float* b1  = (const float*)d_in[7];
  float* out = (float*)d_out;

  char* ws = (char*)d_ws;
  size_t off = 0;
  auto alloc = [&](size_t bytes) -> void* {
    void* p = ws + off;
    off += (bytes + 255) & ~(size_t)255;
    return p;
  };
  float*  h      = (float*)alloc((size_t)N_NODES * HIDDEN * 4);
  ushort* x0     = (ushort*)alloc((size_t)N_EDGES * FEAT * 2);
  ushort* eA     = (ushort*)alloc((size_t)N_EDGES * FEAT * 2);
  ushort* eB     = (ushort*)alloc((size_t)N_EDGES * FEAT * 2);
  ushort* Btp    = (ushort*)alloc((size_t)NUM_LAYERS * FEAT * FEAT * 2);
  ushort* Btp2   = (ushort*)alloc((size_t)NUM_LAYERS * FEAT * FEAT * 2);
  ushort* W1f    = (ushort*)alloc((size_t)FEAT * OUT_FEAT * 2);
  int*    deg    = (int*)alloc((size_t)N_EDGES * 4);
  float*  dis    = (float*)alloc((size_t)N_EDGES * 4);
  int*    cnt    = (int*)alloc((size_t)N_EDGES * 4);
  int*    row_ptr= (int*)alloc((size_t)(N_EDGES + 1) * 4);
  uint2*  pv     = (uint2*)alloc(((size_t)N_TOTE + 32) * 8);  // +pad for unguarded loads
  int*    bsum   = (int*)alloc(256 * 4);

  k_lin0<<<(N_NODES + 3) / 4, 256, 0, stream>>>(x, w0, b0, h);
  k_build_e<<<(N_EDGES * 32 + 255) / 256, 256, 0, stream>>>(ei, ei + N_EDGES, h, eA, x0);
  k_init<<<(N_EDGES + 255) / 256, 256, 0, stream>>>(deg, cnt);
  k_count<<<(N_LEDGES / 4 + 255) / 256, 256, 0, stream>>>((const int4*)lei,
                                                          (const int4*)(lei + N_LEDGES), deg, cnt);
  k_dis<<<(N_EDGES + 255) / 256, 256, 0, stream>>>(deg, dis);
  const int nscan = (N_EDGES + 1023) / 1024;  // 157
  k_scanA<<<nscan, 256, 0, stream>>>(cnt, row_ptr, bsum);
  k_scanB<<<1, 256, 0, stream>>>(bsum, nscan);
  k_scanC<<<nscan, 256, 0, stream>>>(row_ptr, bsum);
  k_fill<<<(N_LEDGES + 255) / 256, 256, 0, stream>>>(lei, lei + N_LEDGES, row_ptr, cnt, dis, pv);
  k_fill_self<<<(N_EDGES + 255) / 256, 256, 0, stream>>>(row_ptr, cnt, dis, pv);
  k_prepw<<<(NUM_LAYERS * FEAT * FEAT + 255) / 256, 256, 0, stream>>>(cw, Btp, Btp2);
  k_prepw1<<<(FEAT * OUT_FEAT + 255) / 256, 256, 0, stream>>>(w1, W1f);

  ushort* ein = eA;
  ushort* eout = eB;
  for (int l = 0; l < NUM_LAYERS - 1; l++) {
    k_layer<<<N_EDGES / 64, 256, 0, stream>>>(row_ptr, pv, ein, x0,
                                              Btp + ((size_t)l << 14),
                                              Btp2 + ((size_t)l << 14), eout);
    ushort* t = ein; ein = eout; eout = t;
  }
  k_layer_last<<<N_EDGES / 64, 256, 0, stream>>>(row_ptr, pv, ein, x0,
                                                 Btp + ((size_t)(NUM_LAYERS - 1) << 14),
                                                 Btp2 + ((size_t)(NUM_LAYERS - 1) << 14),
                                                 W1f, b1, out);
}

// Round 7
// 964.848 us; speedup vs baseline: 1.2234x; 1.0015x over previous
//
#include <hip/hip_runtime.h>
#include <math.h>

#define N_NODES   20000
#define N_EDGES   160000
#define N_LEDGES  1280000
#define N_TOTE    (N_LEDGES + N_EDGES)   // edges incl. self-loops
#define IN_FEAT   128
#define HIDDEN    64
#define FEAT      128
#define OUT_FEAT  16
#define NUM_LAYERS 8
#define ALPHA     0.1f
#define CHUNK     8

typedef __attribute__((ext_vector_type(4))) float f32x4;
typedef __attribute__((ext_vector_type(8))) short bf16x8;

__device__ __forceinline__ float2 bf2(uint u) {
  union { uint i; float f; } a, b;
  a.i = u << 16;
  b.i = u & 0xffff0000u;
  float2 r; r.x = a.f; r.y = b.f; return r;
}
__device__ __forceinline__ ushort f2bf(float f) {
  union { float f; uint i; } u; u.f = f;
  uint r = u.i + 0x7fffu + ((u.i >> 16) & 1u);
  return (ushort)(r >> 16);
}
__device__ __forceinline__ uint pack2(float x, float y) {
  return (uint)f2bf(x) | ((uint)f2bf(y) << 16);
}

// ---------------- fused pre-pass: lin0 | init | prepw | prepw1 ----------------
// blocks [0,5000): lin0 ; [5000,5625): init ; [5625,6137): prepw ; [6137,6145): prepw1
__global__ __launch_bounds__(256) void k_pre(const float* __restrict__ x,
                                             const float* __restrict__ w0,
                                             const float* __restrict__ b0,
                                             float* __restrict__ h,
                                             int* __restrict__ deg,
                                             int* __restrict__ cnt,
                                             const float* __restrict__ W,
                                             ushort* __restrict__ Bt,
                                             ushort* __restrict__ Bt2,
                                             const float* __restrict__ W1,
                                             ushort* __restrict__ W1f) {
  int bid = blockIdx.x;
  int tid = threadIdx.x;
  if (bid < 5000) {
    // lin0 + relu: h[20000,64]
    int node = bid * 4 + (tid >> 6);
    int j = tid & 63;
    const float* xr = x + (size_t)node * IN_FEAT;
    float acc = b0[j];
    #pragma unroll
    for (int k = 0; k < IN_FEAT; k++) acc = fmaf(xr[k], w0[k * HIDDEN + j], acc);
    h[(size_t)node * HIDDEN + j] = fmaxf(acc, 0.f);
  } else if (bid < 5625) {
    int i = (bid - 5000) * 256 + tid;
    if (i < N_EDGES) { deg[i] = 0; cnt[i] = 1; }  // self-loop pre-counted
  } else if (bid < 6137) {
    // Bt[l][c][k] = bf16(beta*W[l][k][c] + (k==c)*(1-beta)); Bt2 = 0.1*Bt
    int gid = (bid - 5625) * 256 + tid;  // < 131072 exactly
    int l = gid >> 14;
    int rem = gid & 16383;
    int k = rem >> 7, c = rem & 127;
    float beta = logf(0.5f / (float)(l + 1) + 1.0f);
    float v = beta * W[gid];
    if (k == c) v += 1.0f - beta;
    int o = (l << 14) + (c << 7) + k;
    Bt[o]  = f2bf(v);
    Bt2[o] = f2bf(ALPHA * v);
  } else {
    int gid = (bid - 6137) * 256 + tid;
    if (gid < FEAT * OUT_FEAT) {
      int k = gid >> 4, c = gid & 15;
      W1f[c * FEAT + k] = f2bf(W1[gid]);
    }
  }
}

// ---------------- fused: build_e | count ----------------
// blocks [0,20000): e[i]=[h[src]||h[dst]], x0=e ; [20000,21250): deg/cnt atomics
__global__ __launch_bounds__(256) void k_bec(const int* __restrict__ src,
                                             const int* __restrict__ dst,
                                             const float* __restrict__ h,
                                             ushort* __restrict__ e,
                                             ushort* __restrict__ x0,
                                             const int4* __restrict__ lrow4,
                                             const int4* __restrict__ lcol4,
                                             int* __restrict__ deg,
                                             int* __restrict__ cnt) {
  int bid = blockIdx.x;
  int tid = threadIdx.x;
  if (bid < 20000) {
    int gid = bid * 256 + tid;
    int edge = gid >> 5;
    int p = gid & 31;
    int n = (p < 16) ? src[edge] : dst[edge];
    float4 v = ((const float4*)(h + (size_t)n * HIDDEN))[p & 15];
    uint2 pk;
    pk.x = pack2(v.x, v.y);
    pk.y = pack2(v.z, v.w);
    ((uint2*)(e  + ((size_t)edge << 7)))[p] = pk;
    ((uint2*)(x0 + ((size_t)edge << 7)))[p] = pk;
  } else {
    int k = (bid - 20000) * 256 + tid;
    if (k < N_LEDGES / 4) {
      int4 r = lrow4[k], c = lcol4[k];
      atomicAdd(&deg[c.x], 1); atomicAdd(&deg[c.y], 1);
      atomicAdd(&deg[c.z], 1); atomicAdd(&deg[c.w], 1);
      atomicAdd(&cnt[r.x], 1); atomicAdd(&cnt[r.y], 1);
      atomicAdd(&cnt[r.z], 1); atomicAdd(&cnt[r.w], 1);
    }
  }
}

__global__ __launch_bounds__(256) void k_dis(const int* __restrict__ deg,
                                             float* __restrict__ dis) {
  int i = blockIdx.x * 256 + threadIdx.x;
  if (i < N_EDGES) dis[i] = rsqrtf((float)(deg[i] + 1));  // +1 self-loop
}

// ---------------- exclusive scan of cnt -> row_ptr ----------------
__global__ __launch_bounds__(256) void k_scanA(const int* __restrict__ cnt,
                                               int* __restrict__ out,
                                               int* __restrict__ bsum) {
  __shared__ int sh[256];
  int tid = threadIdx.x;
  int base = blockIdx.x * 1024 + tid * 4;
  int v[4];
  #pragma unroll
  for (int i = 0; i < 4; i++) v[i] = (base + i < N_EDGES) ? cnt[base + i] : 0;
  int t = v[0] + v[1] + v[2] + v[3];
  sh[tid] = t;
  __syncthreads();
  for (int off = 1; off < 256; off <<= 1) {
    int xv = (tid >= off) ? sh[tid - off] : 0;
    __syncthreads();
    sh[tid] += xv;
    __syncthreads();
  }
  int run = sh[tid] - t;
  #pragma unroll
  for (int i = 0; i < 4; i++) {
    if (base + i < N_EDGES) out[base + i] = run;
    run += v[i];
  }
  if (tid == 255) bsum[blockIdx.x] = sh[255];
}

__global__ void k_scanB(int* __restrict__ bsum, int nb) {
  __shared__ int sh[256];
  int tid = threadIdx.x;
  int v = (tid < nb) ? bsum[tid] : 0;
  sh[tid] = v;
  __syncthreads();
  for (int off = 1; off < 256; off <<= 1) {
    int xv = (tid >= off) ? sh[tid - off] : 0;
    __syncthreads();
    sh[tid] += xv;
    __syncthreads();
  }
  if (tid < nb) bsum[tid] = sh[tid] - v;  // exclusive
}

__global__ __launch_bounds__(256) void k_scanC(int* __restrict__ row_ptr,
                                               const int* __restrict__ bsum) {
  int tid = threadIdx.x;
  int base = blockIdx.x * 1024 + tid * 4;
  int add = bsum[blockIdx.x];
  #pragma unroll
  for (int i = 0; i < 4; i++)
    if (base + i < N_EDGES) row_ptr[base + i] += add;
  if (blockIdx.x == 0 && tid == 0) row_ptr[N_EDGES] = N_TOTE;
}

// ---------------- fused fill: real edges + self-loops ----------------
__global__ __launch_bounds__(256) void k_fillall(const int* __restrict__ lrow,
                                                 const int* __restrict__ lcol,
                                                 const int* __restrict__ row_ptr,
                                                 int* __restrict__ cnt,
                                                 const float* __restrict__ dis,
                                                 uint2* __restrict__ pv) {
  int k = blockIdx.x * 256 + threadIdx.x;
  if (k < N_LEDGES) {
    int r = lrow[k], c = lcol[k];
    int pos = row_ptr[r] + atomicSub(&cnt[r], 1) - 1;
    uint2 out;
    out.x = (uint)c;
    out.y = __float_as_uint((1.f - ALPHA) * dis[r] * dis[c]);
    pv[pos] = out;
  } else {
    int r = k - N_LEDGES;
    if (r < N_EDGES) {
      int pos = row_ptr[r] + atomicSub(&cnt[r], 1) - 1;
      float d = dis[r];
      uint2 out;
      out.x = (uint)r;
      out.y = __float_as_uint((1.f - ALPHA) * d * d);
      pv[pos] = out;
    }
  }
}

// ---------------- gather phase: segmented stream, SALU broadcast, 8 in flight ----------------
// pv loaded 16 entries/line (one coalesced 128B load per 16 edges); entry
// broadcast via v_readlane (SALU, no LDS round-trip); gather base in SGPR.
__device__ __forceinline__ void gather_phase(const int* __restrict__ row_ptr,
                                             const uint2* __restrict__ pv,
                                             const uint* __restrict__ eu,
                                             ushort* As, int row0, int wv, int lane) {
  int r0w = row0 + wv * 16;
  int rpidx = r0w + lane;
  if (rpidx > N_EDGES) rpidx = N_EDGES;
  int myrp = row_ptr[rpidx];

  int t    = __builtin_amdgcn_readlane(myrp, 0);
  int tend = __builtin_amdgcn_readlane(myrp, 16);
  int r    = r0w;
  int end  = __builtin_amdgcn_readlane(myrp, 1);

  float ax = 0.f, ay = 0.f;
  uint uA[CHUNK], uB[CHUNK];
  uint2 P, Pn;

  auto loadpv16 = [&](int tb_, uint2& p) {
    p = pv[tb_ + (lane & 15)];            // 128B line, covers 2 chunks
  };
  auto gather8 = [&](int tb_, const uint2& p, int base, uint* uu) {
    #pragma unroll
    for (int j = 0; j < CHUNK; j++) {
      int cu = (tb_ + j < tend)
                 ? __builtin_amdgcn_readlane((int)p.x, base + j)
                 : 0;
      uu[j] = eu[((size_t)cu << 6) + lane];
    }
  };
  auto flush = [&]() {
    int rl = r - row0;
    *(uint*)((char*)As + rl * 256 + ((lane * 4) ^ ((rl & 7) << 4))) = pack2(ax, ay);
    ax = 0.f; ay = 0.f;
  };
  auto consume8 = [&](int tb_, const uint2& p, int base, const uint* uu) {
    #pragma unroll
    for (int j = 0; j < CHUNK; j++) {
      int tj = tb_ + j;
      if (tj < tend) {                      // wave-uniform
        while (tj >= end) {                 // row boundary (wave-uniform)
          flush();
          r++;
          end = __builtin_amdgcn_readlane(myrp, r - r0w + 1);
        }
        float v = __uint_as_float(__builtin_amdgcn_readlane((int)p.y, base + j));
        float2 f = bf2(uu[j]);
        ax = fmaf(v, f.x, ax);
        ay = fmaf(v, f.y, ay);
      }
    }
  };

  int tb = t;
  loadpv16(tb, P);
  gather8(tb, P, 0, uA);
  while (true) {
    loadpv16(tb + 16, Pn);                  // pv for chunks +2,+3
    gather8(tb + CHUNK, P, 8, uB);
    consume8(tb, P, 0, uA);
    tb += CHUNK;
    if (tb >= tend) break;
    gather8(tb + CHUNK, Pn, 0, uA);
    consume8(tb, P, 8, uB);
    tb += CHUNK;
    if (tb >= tend) break;
    P = Pn;
  }
  flush();  // last row (every row has >=1 edge via self-loop)
}

// ---------------- MFMA accumulate: acc = As@W' + x0tile@W2 ----------------
__device__ __forceinline__ void mfma_accum(const ushort* As,
                                           const ushort* __restrict__ x0,
                                           const ushort* __restrict__ Bt,
                                           const ushort* __restrict__ Bt2,
                                           int row0, int wv, int l15, int l4,
                                           f32x4 acc[4][2]) {
  const char* btA  = (const char*)Bt  + (size_t)(wv * 32 + l15) * 256;
  const char* btB  = btA + 16 * 256;
  const char* bt2A = (const char*)Bt2 + (size_t)(wv * 32 + l15) * 256;
  const char* bt2B = bt2A + 16 * 256;
  const char* x0b  = (const char*)x0 + ((size_t)row0 << 8);
  #pragma unroll
  for (int kb = 0; kb < 4; kb++) {
    int kbyte = kb * 64 + l4 * 16;
    bf16x8 b0 = *(const bf16x8*)(btA + kbyte);
    bf16x8 b1 = *(const bf16x8*)(btB + kbyte);
    bf16x8 q0 = *(const bf16x8*)(bt2A + kbyte);
    bf16x8 q1 = *(const bf16x8*)(bt2B + kbyte);
    #pragma unroll
    for (int mr = 0; mr < 4; mr++) {
      int rr = mr * 16 + l15;
      bf16x8 afr = *(const bf16x8*)((const char*)As + rr * 256 + (kbyte ^ ((rr & 7) << 4)));
      bf16x8 xfr = *(const bf16x8*)(x0b + (size_t)rr * 256 + kbyte);
      acc[mr][0] = __builtin_amdgcn_mfma_f32_16x16x32_bf16(afr, b0, acc[mr][0], 0, 0, 0);
      acc[mr][1] = __builtin_amdgcn_mfma_f32_16x16x32_bf16(afr, b1, acc[mr][1], 0, 0, 0);
      acc[mr][0] = __builtin_amdgcn_mfma_f32_16x16x32_bf16(xfr, q0, acc[mr][0], 0, 0, 0);
      acc[mr][1] = __builtin_amdgcn_mfma_f32_16x16x32_bf16(xfr, q1, acc[mr][1], 0, 0, 0);
    }
  }
}

// ---------------- fused layer (layers 0..6): -> e_out bf16 ----------------
__global__ __launch_bounds__(256, 6) void k_layer(const int* __restrict__ row_ptr,
                                                  const uint2* __restrict__ pv,
                                                  const ushort* __restrict__ e_in,
                                                  const ushort* __restrict__ x0,
                                                  const ushort* __restrict__ Bt,
                                                  const ushort* __restrict__ Bt2,
                                                  ushort* __restrict__ e_out) {
  __shared__ __align__(16) ushort As[64 * 128];  // 16KB
  int tid = threadIdx.x;
  int wv = tid >> 6, lane = tid & 63;
  int l15 = lane & 15, l4 = lane >> 4;
  int row0 = blockIdx.x * 64;

  gather_phase(row_ptr, pv, (const uint*)e_in, As, row0, wv, lane);
  __syncthreads();

  f32x4 acc[4][2];
  #pragma unroll
  for (int i = 0; i < 4; i++) { acc[i][0] = (f32x4)0; acc[i][1] = (f32x4)0; }
  mfma_accum(As, x0, Bt, Bt2, row0, wv, l15, l4, acc);

  __syncthreads();  // all waves done reading As
  // stage relu(acc) into As as [row][col] bf16 (XOR bits 4-6 per row)
  #pragma unroll
  for (int mr = 0; mr < 4; mr++) {
    #pragma unroll
    for (int n = 0; n < 2; n++) {
      int col = wv * 32 + n * 16 + l15;
      #pragma unroll
      for (int j = 0; j < 4; j++) {
        int rl = mr * 16 + l4 * 4 + j;
        float v = fmaxf(acc[mr][n][j], 0.f);
        *(ushort*)((char*)As + rl * 256 + ((col * 2) ^ ((rl & 7) << 4))) = f2bf(v);
      }
    }
  }
  __syncthreads();
  // full-line coalesced copy-out: 1024 16B chunks
  const char* asb = (const char*)As;
  #pragma unroll
  for (int k2 = 0; k2 < 4; k2++) {
    int q = k2 * 256 + tid;
    int rl = q >> 4, ck = q & 15;
    uint4 v = *(const uint4*)(asb + rl * 256 + ((ck * 16) ^ ((rl & 7) << 4)));
    *(uint4*)((char*)e_out + (((size_t)(row0 + rl)) << 8) + ck * 16) = v;
  }
}

// ---------------- last layer: fused lin1, writes out fp32 ----------------
__global__ __launch_bounds__(256, 4) void k_layer_last(const int* __restrict__ row_ptr,
                                                       const uint2* __restrict__ pv,
                                                       const ushort* __restrict__ e_in,
                                                       const ushort* __restrict__ x0,
                                                       const ushort* __restrict__ Bt,
                                                       const ushort* __restrict__ Bt2,
                                                       const ushort* __restrict__ W1f,
                                                       const float* __restrict__ b1,
                                                       float* __restrict__ out) {
  __shared__ __align__(16) ushort As[64 * 128];  // 16KB
  int tid = threadIdx.x;
  int wv = tid >> 6, lane = tid & 63;
  int l15 = lane & 15, l4 = lane >> 4;
  int row0 = blockIdx.x * 64;

  gather_phase(row_ptr, pv, (const uint*)e_in, As, row0, wv, lane);
  __syncthreads();

  f32x4 acc[4][2];
  #pragma unroll
  for (int i = 0; i < 4; i++) { acc[i][0] = (f32x4)0; acc[i][1] = (f32x4)0; }
  mfma_accum(As, x0, Bt, Bt2, row0, wv, l15, l4, acc);

  __syncthreads();  // all waves done reading As
  // relu -> bf16 e-tile back into As (swizzled)
  #pragma unroll
  for (int mr = 0; mr < 4; mr++) {
    #pragma unroll
    for (int n = 0; n < 2; n++) {
      int col = wv * 32 + n * 16 + l15;
      #pragma unroll
      for (int j = 0; j < 4; j++) {
        int rl = mr * 16 + l4 * 4 + j;
        float v = fmaxf(acc[mr][n][j], 0.f);
        *(ushort*)((char*)As + rl * 256 + ((col * 2) ^ ((rl & 7) << 4))) = f2bf(v);
      }
    }
  }
  __syncthreads();

  // lin1: out(64x16) = e_tile(64x128) @ W1(128x16) + b1
  f32x4 acc2[4];
  #pragma unroll
  for (int i = 0; i < 4; i++) acc2[i] = (f32x4)0;
  const char* w1p = (const char*)W1f + (size_t)l15 * 256;
  #pragma unroll
  for (int kb = 0; kb < 4; kb++) {
    int kbyte = kb * 64 + l4 * 16;
    bf16x8 wfr = *(const bf16x8*)(w1p + kbyte);
    #pragma unroll
    for (int mr = 0; mr < 4; mr++) {
      int rr = mr * 16 + l15;
      bf16x8 afr = *(const bf16x8*)((const char*)As + rr * 256 + (kbyte ^ ((rr & 7) << 4)));
      acc2[mr] = __builtin_amdgcn_mfma_f32_16x16x32_bf16(afr, wfr, acc2[mr], 0, 0, 0);
    }
  }
  float bias = b1[l15];
  #pragma unroll
  for (int mr = 0; mr < 4; mr++) {
    int rowb = row0 + mr * 16 + l4 * 4;
    #pragma unroll
    for (int j = 0; j < 4; j++)
      out[(size_t)(rowb + j) * OUT_FEAT + l15] = acc2[mr][j] + bias;
  }
}

extern "C" void kernel_launch(void* const* d_in, const int* in_sizes, int n_in,
                              void* d_out, int out_size, void* d_ws, size_t ws_size,
                              hipStream_t stream) {
  const float* x   = (const float*)d_in[0];
  const int*   ei  = (const int*)d_in[1];
  const int*   lei = (const int*)d_in[2];
  const float* w0  = (const float*)d_in[3];
  const float* b0  = (const float*)d_in[4];
  const float* cw  = (const float*)d_in[5];
  const float* w1  = (const float*)d_in[6];
  const float* b1  = (const float*)d_in[7];
  float* out = (float*)d_out;

  char* ws = (char*)d_ws;
  size_t off = 0;
  auto alloc = [&](size_t bytes) -> void* {
    void* p = ws + off;
    off += (bytes + 255) & ~(size_t)255;
    return p;
  };
  float*  h      = (float*)alloc((size_t)N_NODES * HIDDEN * 4);
  ushort* x0     = (ushort*)alloc((size_t)N_EDGES * FEAT * 2);
  ushort* eA     = (ushort*)alloc((size_t)N_EDGES * FEAT * 2);
  ushort* eB     = (ushort*)alloc((size_t)N_EDGES * FEAT * 2);
  ushort* Btp    = (ushort*)alloc((size_t)NUM_LAYERS * FEAT * FEAT * 2);
  ushort* Btp2   = (ushort*)alloc((size_t)NUM_LAYERS * FEAT * FEAT * 2);
  ushort* W1f    = (ushort*)alloc((size_t)FEAT * OUT_FEAT * 2);
  int*    deg    = (int*)alloc((size_t)N_EDGES * 4);
  float*  dis    = (float*)alloc((size_t)N_EDGES * 4);
  int*    cnt    = (int*)alloc((size_t)N_EDGES * 4);
  int*    row_ptr= (int*)alloc((size_t)(N_EDGES + 1) * 4);
  uint2*  pv     = (uint2*)alloc(((size_t)N_TOTE + 32) * 8);  // +pad for unguarded loads
  int*    bsum   = (int*)alloc(256 * 4);

  // pre-pass: lin0 | init | prepw | prepw1 (all independent)
  k_pre<<<6145, 256, 0, stream>>>(x, w0, b0, h, deg, cnt, cw, Btp, Btp2, w1, W1f);
  // build_e | count (build_e depends on h; count only on lei)
  k_bec<<<21250, 256, 0, stream>>>(ei, ei + N_EDGES, h, eA, x0,
                                   (const int4*)lei, (const int4*)(lei + N_LEDGES), deg, cnt);
  k_dis<<<(N_EDGES + 255) / 256, 256, 0, stream>>>(deg, dis);
  const int nscan = (N_EDGES + 1023) / 1024;  // 157
  k_scanA<<<nscan, 256, 0, stream>>>(cnt, row_ptr, bsum);
  k_scanB<<<1, 256, 0, stream>>>(bsum, nscan);
  k_scanC<<<nscan, 256, 0, stream>>>(row_ptr, bsum);
  k_fillall<<<(N_TOTE + 255) / 256, 256, 0, stream>>>(lei, lei + N_LEDGES, row_ptr, cnt, dis, pv);

  ushort* ein = eA;
  ushort* eout = eB;
  for (int l = 0; l < NUM_LAYERS - 1; l++) {
    k_layer<<<N_EDGES / 64, 256, 0, stream>>>(row_ptr, pv, ein, x0,
                                              Btp + ((size_t)l << 14),
                                              Btp2 + ((size_t)l << 14), eout);
    ushort* t = ein; ein = eout; eout = t;
  }
  k_layer_last<<<N_EDGES / 64, 256, 0, stream>>>(row_ptr, pv, ein, x0,
                                                 Btp + ((size_t)(NUM_LAYERS - 1) << 14),
                                                 Btp2 + ((size_t)(NUM_LAYERS - 1) << 14),
                                                 W1f, b1, out);
}

// Round 8
// 816.052 us; speedup vs baseline: 1.4465x; 1.1823x over previous
//
#include <hip/hip_runtime.h>
#include <math.h>

#define N_NODES   20000
#define N_EDGES   160000
#define N_LEDGES  1280000
#define N_TOTE    (N_LEDGES + N_EDGES)   // edges incl. self-loops
#define IN_FEAT   128
#define HIDDEN    64
#define FEAT      128
#define OUT_FEAT  16
#define NUM_LAYERS 8
#define ALPHA     0.1f
#define CHUNK     8

typedef __attribute__((ext_vector_type(4))) float f32x4;
typedef __attribute__((ext_vector_type(8))) short bf16x8;

__device__ __forceinline__ float2 bf2(uint u) {
  union { uint i; float f; } a, b;
  a.i = u << 16;
  b.i = u & 0xffff0000u;
  float2 r; r.x = a.f; r.y = b.f; return r;
}
__device__ __forceinline__ ushort f2bf(float f) {
  union { float f; uint i; } u; u.f = f;
  uint r = u.i + 0x7fffu + ((u.i >> 16) & 1u);
  return (ushort)(r >> 16);
}
__device__ __forceinline__ uint pack2(float x, float y) {
  return (uint)f2bf(x) | ((uint)f2bf(y) << 16);
}

// ---------------- fused pre-pass: lin0 | init | prepw | prepw1 ----------------
// blocks [0,5000): lin0 ; [5000,5625): init ; [5625,6137): prepw ; [6137,6145): prepw1
__global__ __launch_bounds__(256) void k_pre(const float* __restrict__ x,
                                             const float* __restrict__ w0,
                                             const float* __restrict__ b0,
                                             float* __restrict__ h,
                                             int* __restrict__ deg,
                                             int* __restrict__ cnt,
                                             const float* __restrict__ W,
                                             ushort* __restrict__ Bt,
                                             const float* __restrict__ W1,
                                             ushort* __restrict__ W1f) {
  int bid = blockIdx.x;
  int tid = threadIdx.x;
  if (bid < 5000) {
    // lin0 + relu: h[20000,64]
    int node = bid * 4 + (tid >> 6);
    int j = tid & 63;
    const float* xr = x + (size_t)node * IN_FEAT;
    float acc = b0[j];
    #pragma unroll
    for (int k = 0; k < IN_FEAT; k++) acc = fmaf(xr[k], w0[k * HIDDEN + j], acc);
    h[(size_t)node * HIDDEN + j] = fmaxf(acc, 0.f);
  } else if (bid < 5625) {
    int i = (bid - 5000) * 256 + tid;
    if (i < N_EDGES) { deg[i] = 0; cnt[i] = 1; }  // self-loop pre-counted
  } else if (bid < 6137) {
    // Bt[l][c][k] = bf16(beta*W[l][k][c] + (k==c)*(1-beta))
    int gid = (bid - 5625) * 256 + tid;  // < 131072 exactly
    int l = gid >> 14;
    int rem = gid & 16383;
    int k = rem >> 7, c = rem & 127;
    float beta = logf(0.5f / (float)(l + 1) + 1.0f);
    float v = beta * W[gid];
    if (k == c) v += 1.0f - beta;
    Bt[(l << 14) + (c << 7) + k] = f2bf(v);
  } else {
    int gid = (bid - 6137) * 256 + tid;
    if (gid < FEAT * OUT_FEAT) {
      int k = gid >> 4, c = gid & 15;
      W1f[c * FEAT + k] = f2bf(W1[gid]);
    }
  }
}

// ---------------- fused: build_e | XCD-local count ----------------
// blocks [0,20000): e[i]=[h[src]||h[dst]], x0=e
// blocks [20000,20000+8*313): class-partitioned histogram (class = bid%8,
// counts only indices in [class*20000,(class+1)*20000) -> atomics stay on
// one XCD's L2 under round-robin dispatch; correct under any mapping).
#define CNT_SLICES 313
__global__ __launch_bounds__(256) void k_bec(const int* __restrict__ src,
                                             const int* __restrict__ dst,
                                             const float* __restrict__ h,
                                             ushort* __restrict__ e,
                                             ushort* __restrict__ x0,
                                             const int4* __restrict__ lrow4,
                                             const int4* __restrict__ lcol4,
                                             int* __restrict__ deg,
                                             int* __restrict__ cnt) {
  int bid = blockIdx.x;
  int tid = threadIdx.x;
  if (bid < 20000) {
    int gid = bid * 256 + tid;
    int edge = gid >> 5;
    int p = gid & 31;
    int n = (p < 16) ? src[edge] : dst[edge];
    float4 v = ((const float4*)(h + (size_t)n * HIDDEN))[p & 15];
    uint2 pk;
    pk.x = pack2(v.x, v.y);
    pk.y = pack2(v.z, v.w);
    ((uint2*)(e  + ((size_t)edge << 7)))[p] = pk;
    ((uint2*)(x0 + ((size_t)edge << 7)))[p] = pk;
  } else {
    int q = bid - 20000;
    int cls = bid & 7;                 // == (20000+q)%8 since 20000%8==0
    int s = q >> 3;
    int lo = cls * 20000, hi = lo + 20000;
    #pragma unroll
    for (int i = 0; i < 4; i++) {
      int idx4 = s * 1024 + i * 256 + tid;
      if (idx4 < N_LEDGES / 4) {
        int4 r = lrow4[idx4], c = lcol4[idx4];
        if (c.x >= lo && c.x < hi) atomicAdd(&deg[c.x], 1);
        if (c.y >= lo && c.y < hi) atomicAdd(&deg[c.y], 1);
        if (c.z >= lo && c.z < hi) atomicAdd(&deg[c.z], 1);
        if (c.w >= lo && c.w < hi) atomicAdd(&deg[c.w], 1);
        if (r.x >= lo && r.x < hi) atomicAdd(&cnt[r.x], 1);
        if (r.y >= lo && r.y < hi) atomicAdd(&cnt[r.y], 1);
        if (r.z >= lo && r.z < hi) atomicAdd(&cnt[r.z], 1);
        if (r.w >= lo && r.w < hi) atomicAdd(&cnt[r.w], 1);
      }
    }
  }
}

__global__ __launch_bounds__(256) void k_dis(const int* __restrict__ deg,
                                             float* __restrict__ dis) {
  int i = blockIdx.x * 256 + threadIdx.x;
  if (i < N_EDGES) dis[i] = rsqrtf((float)(deg[i] + 1));  // +1 self-loop
}

// ---------------- exclusive scan of cnt -> row_ptr ----------------
__global__ __launch_bounds__(256) void k_scanA(const int* __restrict__ cnt,
                                               int* __restrict__ out,
                                               int* __restrict__ bsum) {
  __shared__ int sh[256];
  int tid = threadIdx.x;
  int base = blockIdx.x * 1024 + tid * 4;
  int v[4];
  #pragma unroll
  for (int i = 0; i < 4; i++) v[i] = (base + i < N_EDGES) ? cnt[base + i] : 0;
  int t = v[0] + v[1] + v[2] + v[3];
  sh[tid] = t;
  __syncthreads();
  for (int off = 1; off < 256; off <<= 1) {
    int xv = (tid >= off) ? sh[tid - off] : 0;
    __syncthreads();
    sh[tid] += xv;
    __syncthreads();
  }
  int run = sh[tid] - t;
  #pragma unroll
  for (int i = 0; i < 4; i++) {
    if (base + i < N_EDGES) out[base + i] = run;
    run += v[i];
  }
  if (tid == 255) bsum[blockIdx.x] = sh[255];
}

__global__ void k_scanB(int* __restrict__ bsum, int nb) {
  __shared__ int sh[256];
  int tid = threadIdx.x;
  int v = (tid < nb) ? bsum[tid] : 0;
  sh[tid] = v;
  __syncthreads();
  for (int off = 1; off < 256; off <<= 1) {
    int xv = (tid >= off) ? sh[tid - off] : 0;
    __syncthreads();
    sh[tid] += xv;
    __syncthreads();
  }
  if (tid < nb) bsum[tid] = sh[tid] - v;  // exclusive
}

__global__ __launch_bounds__(256) void k_scanC(int* __restrict__ row_ptr,
                                               const int* __restrict__ bsum) {
  int tid = threadIdx.x;
  int base = blockIdx.x * 1024 + tid * 4;
  int add = bsum[blockIdx.x];
  #pragma unroll
  for (int i = 0; i < 4; i++)
    if (base + i < N_EDGES) row_ptr[base + i] += add;
  if (blockIdx.x == 0 && tid == 0) row_ptr[N_EDGES] = N_TOTE;
}

// ---------------- fused fill: real edges + self-loops ----------------
__global__ __launch_bounds__(256) void k_fillall(const int* __restrict__ lrow,
                                                 const int* __restrict__ lcol,
                                                 const int* __restrict__ row_ptr,
                                                 int* __restrict__ cnt,
                                                 const float* __restrict__ dis,
                                                 uint2* __restrict__ pv) {
  int k = blockIdx.x * 256 + threadIdx.x;
  if (k < N_LEDGES) {
    int r = lrow[k], c = lcol[k];
    int pos = row_ptr[r] + atomicSub(&cnt[r], 1) - 1;
    uint2 out;
    out.x = (uint)c;
    out.y = __float_as_uint((1.f - ALPHA) * dis[r] * dis[c]);
    pv[pos] = out;
  } else {
    int r = k - N_LEDGES;
    if (r < N_EDGES) {
      int pos = row_ptr[r] + atomicSub(&cnt[r], 1) - 1;
      float d = dis[r];
      uint2 out;
      out.x = (uint)r;
      out.y = __float_as_uint((1.f - ALPHA) * d * d);
      pv[pos] = out;
    }
  }
}

// ---------------- gather phase: segmented stream + alpha*x0 folded at flush ----
// pv loaded 16 entries/line; entry broadcast via v_readlane (SALU); gather
// base in SGPR. x0 row prefetched one row ahead (latency hidden under the
// row's edge gathers); As[r] = sum(0.9*val*e[c]) + 0.1*x0[r] = m[r].
__device__ __forceinline__ void gather_phase(const int* __restrict__ row_ptr,
                                             const uint2* __restrict__ pv,
                                             const uint* __restrict__ eu,
                                             const uint* __restrict__ x0u,
                                             ushort* As, int row0, int wv, int lane) {
  int r0w = row0 + wv * 16;
  int rpidx = r0w + lane;
  if (rpidx > N_EDGES) rpidx = N_EDGES;
  int myrp = row_ptr[rpidx];

  int t    = __builtin_amdgcn_readlane(myrp, 0);
  int tend = __builtin_amdgcn_readlane(myrp, 16);
  int r    = r0w;
  int end  = __builtin_amdgcn_readlane(myrp, 1);

  float ax = 0.f, ay = 0.f;
  uint uA[CHUNK], uB[CHUNK];
  uint2 P, Pn;
  uint xq = x0u[((size_t)r0w << 6) + lane];   // x0 row prefetch

  auto loadpv16 = [&](int tb_, uint2& p) {
    p = pv[tb_ + (lane & 15)];            // 128B line, covers 2 chunks
  };
  auto gather8 = [&](int tb_, const uint2& p, int base, uint* uu) {
    #pragma unroll
    for (int j = 0; j < CHUNK; j++) {
      int cu = (tb_ + j < tend)
                 ? __builtin_amdgcn_readlane((int)p.x, base + j)
                 : 0;
      uu[j] = eu[((size_t)cu << 6) + lane];
    }
  };
  auto flush = [&]() {
    int rl = r - row0;
    float2 fx = bf2(xq);
    *(uint*)((char*)As + rl * 256 + ((lane * 4) ^ ((rl & 7) << 4))) =
        pack2(fmaf(ALPHA, fx.x, ax), fmaf(ALPHA, fx.y, ay));
    ax = 0.f; ay = 0.f;
    if (r + 1 < r0w + 16) xq = x0u[((size_t)(r + 1) << 6) + lane];  // next row
  };
  auto consume8 = [&](int tb_, const uint2& p, int base, const uint* uu) {
    #pragma unroll
    for (int j = 0; j < CHUNK; j++) {
      int tj = tb_ + j;
      if (tj < tend) {                      // wave-uniform
        while (tj >= end) {                 // row boundary (wave-uniform)
          flush();
          r++;
          end = __builtin_amdgcn_readlane(myrp, r - r0w + 1);
        }
        float v = __uint_as_float(__builtin_amdgcn_readlane((int)p.y, base + j));
        float2 f = bf2(uu[j]);
        ax = fmaf(v, f.x, ax);
        ay = fmaf(v, f.y, ay);
      }
    }
  };

  int tb = t;
  loadpv16(tb, P);
  gather8(tb, P, 0, uA);
  while (true) {
    loadpv16(tb + 16, Pn);                  // pv for chunks +2,+3
    gather8(tb + CHUNK, P, 8, uB);
    consume8(tb, P, 0, uA);
    tb += CHUNK;
    if (tb >= tend) break;
    gather8(tb + CHUNK, Pn, 0, uA);
    consume8(tb, P, 8, uB);
    tb += CHUNK;
    if (tb >= tend) break;
    P = Pn;
  }
  flush();  // last row (every row has >=1 edge via self-loop)
}

// ---------------- MFMA accumulate: acc = As@W' ----------------
__device__ __forceinline__ void mfma_accum(const ushort* As,
                                           const ushort* __restrict__ Bt,
                                           int wv, int l15, int l4,
                                           f32x4 acc[4][2]) {
  const char* btA = (const char*)Bt + (size_t)(wv * 32 + l15) * 256;
  const char* btB = btA + 16 * 256;
  #pragma unroll
  for (int kb = 0; kb < 4; kb++) {
    int kbyte = kb * 64 + l4 * 16;
    bf16x8 b0 = *(const bf16x8*)(btA + kbyte);
    bf16x8 b1 = *(const bf16x8*)(btB + kbyte);
    #pragma unroll
    for (int mr = 0; mr < 4; mr++) {
      int rr = mr * 16 + l15;
      bf16x8 afr = *(const bf16x8*)((const char*)As + rr * 256 + (kbyte ^ ((rr & 7) << 4)));
      acc[mr][0] = __builtin_amdgcn_mfma_f32_16x16x32_bf16(afr, b0, acc[mr][0], 0, 0, 0);
      acc[mr][1] = __builtin_amdgcn_mfma_f32_16x16x32_bf16(afr, b1, acc[mr][1], 0, 0, 0);
    }
  }
}

// ---------------- fused layer (layers 0..6): -> e_out bf16 ----------------
__global__ __launch_bounds__(256, 6) void k_layer(const int* __restrict__ row_ptr,
                                                  const uint2* __restrict__ pv,
                                                  const ushort* __restrict__ e_in,
                                                  const ushort* __restrict__ x0,
                                                  const ushort* __restrict__ Bt,
                                                  ushort* __restrict__ e_out) {
  __shared__ __align__(16) ushort As[64 * 128];  // 16KB
  int tid = threadIdx.x;
  int wv = tid >> 6, lane = tid & 63;
  int l15 = lane & 15, l4 = lane >> 4;
  int row0 = blockIdx.x * 64;

  gather_phase(row_ptr, pv, (const uint*)e_in, (const uint*)x0, As, row0, wv, lane);
  __syncthreads();

  f32x4 acc[4][2];
  #pragma unroll
  for (int i = 0; i < 4; i++) { acc[i][0] = (f32x4)0; acc[i][1] = (f32x4)0; }
  mfma_accum(As, Bt, wv, l15, l4, acc);

  __syncthreads();  // all waves done reading As
  // stage relu(acc) into As as [row][col] bf16 (XOR bits 4-6 per row)
  #pragma unroll
  for (int mr = 0; mr < 4; mr++) {
    #pragma unroll
    for (int n = 0; n < 2; n++) {
      int col = wv * 32 + n * 16 + l15;
      #pragma unroll
      for (int j = 0; j < 4; j++) {
        int rl = mr * 16 + l4 * 4 + j;
        float v = fmaxf(acc[mr][n][j], 0.f);
        *(ushort*)((char*)As + rl * 256 + ((col * 2) ^ ((rl & 7) << 4))) = f2bf(v);
      }
    }
  }
  __syncthreads();
  // full-line coalesced copy-out: 1024 16B chunks
  const char* asb = (const char*)As;
  #pragma unroll
  for (int k2 = 0; k2 < 4; k2++) {
    int q = k2 * 256 + tid;
    int rl = q >> 4, ck = q & 15;
    uint4 v = *(const uint4*)(asb + rl * 256 + ((ck * 16) ^ ((rl & 7) << 4)));
    *(uint4*)((char*)e_out + (((size_t)(row0 + rl)) << 8) + ck * 16) = v;
  }
}

// ---------------- last layer: fused lin1, writes out fp32 ----------------
__global__ __launch_bounds__(256, 4) void k_layer_last(const int* __restrict__ row_ptr,
                                                       const uint2* __restrict__ pv,
                                                       const ushort* __restrict__ e_in,
                                                       const ushort* __restrict__ x0,
                                                       const ushort* __restrict__ Bt,
                                                       const ushort* __restrict__ W1f,
                                                       const float* __restrict__ b1,
                                                       float* __restrict__ out) {
  __shared__ __align__(16) ushort As[64 * 128];  // 16KB
  int tid = threadIdx.x;
  int wv = tid >> 6, lane = tid & 63;
  int l15 = lane & 15, l4 = lane >> 4;
  int row0 = blockIdx.x * 64;

  gather_phase(row_ptr, pv, (const uint*)e_in, (const uint*)x0, As, row0, wv, lane);
  __syncthreads();

  f32x4 acc[4][2];
  #pragma unroll
  for (int i = 0; i < 4; i++) { acc[i][0] = (f32x4)0; acc[i][1] = (f32x4)0; }
  mfma_accum(As, Bt, wv, l15, l4, acc);

  __syncthreads();  // all waves done reading As
  // relu -> bf16 e-tile back into As (swizzled)
  #pragma unroll
  for (int mr = 0; mr < 4; mr++) {
    #pragma unroll
    for (int n = 0; n < 2; n++) {
      int col = wv * 32 + n * 16 + l15;
      #pragma unroll
      for (int j = 0; j < 4; j++) {
        int rl = mr * 16 + l4 * 4 + j;
        float v = fmaxf(acc[mr][n][j], 0.f);
        *(ushort*)((char*)As + rl * 256 + ((col * 2) ^ ((rl & 7) << 4))) = f2bf(v);
      }
    }
  }
  __syncthreads();

  // lin1: out(64x16) = e_tile(64x128) @ W1(128x16) + b1
  f32x4 acc2[4];
  #pragma unroll
  for (int i = 0; i < 4; i++) acc2[i] = (f32x4)0;
  const char* w1p = (const char*)W1f + (size_t)l15 * 256;
  #pragma unroll
  for (int kb = 0; kb < 4; kb++) {
    int kbyte = kb * 64 + l4 * 16;
    bf16x8 wfr = *(const bf16x8*)(w1p + kbyte);
    #pragma unroll
    for (int mr = 0; mr < 4; mr++) {
      int rr = mr * 16 + l15;
      bf16x8 afr = *(const bf16x8*)((const char*)As + rr * 256 + (kbyte ^ ((rr & 7) << 4)));
      acc2[mr] = __builtin_amdgcn_mfma_f32_16x16x32_bf16(afr, wfr, acc2[mr], 0, 0, 0);
    }
  }
  float bias = b1[l15];
  #pragma unroll
  for (int mr = 0; mr < 4; mr++) {
    int rowb = row0 + mr * 16 + l4 * 4;
    #pragma unroll
    for (int j = 0; j < 4; j++)
      out[(size_t)(rowb + j) * OUT_FEAT + l15] = acc2[mr][j] + bias;
  }
}

extern "C" void kernel_launch(void* const* d_in, const int* in_sizes, int n_in,
                              void* d_out, int out_size, void* d_ws, size_t ws_size,
                              hipStream_t stream) {
  const float* x   = (const float*)d_in[0];
  const int*   ei  = (const int*)d_in[1];
  const int*   lei = (const int*)d_in[2];
  const float* w0  = (const float*)d_in[3];
  const float* b0  = (const float*)d_in[4];
  const float* cw  = (const float*)d_in[5];
  const float* w1  = (const float*)d_in[6];
  const float* b1  = (const float*)d_in[7];
  float* out = (float*)d_out;

  char* ws = (char*)d_ws;
  size_t off = 0;
  auto alloc = [&](size_t bytes) -> void* {
    void* p = ws + off;
    off += (bytes + 255) & ~(size_t)255;
    return p;
  };
  float*  h      = (float*)alloc((size_t)N_NODES * HIDDEN * 4);
  ushort* x0     = (ushort*)alloc((size_t)N_EDGES * FEAT * 2);
  ushort* eA     = (ushort*)alloc((size_t)N_EDGES * FEAT * 2);
  ushort* eB     = (ushort*)alloc((size_t)N_EDGES * FEAT * 2);
  ushort* Btp    = (ushort*)alloc((size_t)NUM_LAYERS * FEAT * FEAT * 2);
  ushort* W1f    = (ushort*)alloc((size_t)FEAT * OUT_FEAT * 2);
  int*    deg    = (int*)alloc((size_t)N_EDGES * 4);
  float*  dis    = (float*)alloc((size_t)N_EDGES * 4);
  int*    cnt    = (int*)alloc((size_t)N_EDGES * 4);
  int*    row_ptr= (int*)alloc((size_t)(N_EDGES + 1) * 4);
  uint2*  pv     = (uint2*)alloc(((size_t)N_TOTE + 32) * 8);  // +pad for unguarded loads
  int*    bsum   = (int*)alloc(256 * 4);

  // pre-pass: lin0 | init | prepw | prepw1 (all independent)
  k_pre<<<6145, 256, 0, stream>>>(x, w0, b0, h, deg, cnt, cw, Btp, w1, W1f);
  // build_e | XCD-local count
  k_bec<<<20000 + 8 * CNT_SLICES, 256, 0, stream>>>(ei, ei + N_EDGES, h, eA, x0,
                                   (const int4*)lei, (const int4*)(lei + N_LEDGES), deg, cnt);
  k_dis<<<(N_EDGES + 255) / 256, 256, 0, stream>>>(deg, dis);
  const int nscan = (N_EDGES + 1023) / 1024;  // 157
  k_scanA<<<nscan, 256, 0, stream>>>(cnt, row_ptr, bsum);
  k_scanB<<<1, 256, 0, stream>>>(bsum, nscan);
  k_scanC<<<nscan, 256, 0, stream>>>(row_ptr, bsum);
  k_fillall<<<(N_TOTE + 255) / 256, 256, 0, stream>>>(lei, lei + N_LEDGES, row_ptr, cnt, dis, pv);

  ushort* ein = eA;
  ushort* eout = eB;
  for (int l = 0; l < NUM_LAYERS - 1; l++) {
    k_layer<<<N_EDGES / 64, 256, 0, stream>>>(row_ptr, pv, ein, x0,
                                              Btp + ((size_t)l << 14), eout);
    ushort* t = ein; ein = eout; eout = t;
  }
  k_layer_last<<<N_EDGES / 64, 256, 0, stream>>>(row_ptr, pv, ein, x0,
                                                 Btp + ((size_t)(NUM_LAYERS - 1) << 14),
                                                 W1f, b1, out);
}

// Round 9
// 780.070 us; speedup vs baseline: 1.5132x; 1.0461x over previous
//
#include <hip/hip_runtime.h>
#include <math.h>

#define N_NODES   20000
#define N_EDGES   160000
#define N_LEDGES  1280000
#define N_TOTE    (N_LEDGES + N_EDGES)   // edges incl. self-loops
#define IN_FEAT   128
#define HIDDEN    64
#define FEAT      128
#define OUT_FEAT  16
#define NUM_LAYERS 8
#define ALPHA     0.1f
#define CHUNK     8

typedef __attribute__((ext_vector_type(4))) float f32x4;
typedef __attribute__((ext_vector_type(8))) short bf16x8;

__device__ __forceinline__ float2 bf2(uint u) {
  union { uint i; float f; } a, b;
  a.i = u << 16;
  b.i = u & 0xffff0000u;
  float2 r; r.x = a.f; r.y = b.f; return r;
}
__device__ __forceinline__ ushort f2bf(float f) {
  union { float f; uint i; } u; u.f = f;
  uint r = u.i + 0x7fffu + ((u.i >> 16) & 1u);
  return (ushort)(r >> 16);
}
__device__ __forceinline__ uint pack2(float x, float y) {
  return (uint)f2bf(x) | ((uint)f2bf(y) << 16);
}

// ================= K1: cnt-count(+rank) | lin0 | prepw | prepw1 =================
// blocks [0,1250): cnt histogram over lrow, rank[k] = old count (4 edges/thread)
// blocks [1250,6250): lin0+relu ; [6250,6762): prepw ; [6762,6770): prepw1
__global__ __launch_bounds__(256) void k_pre(const int4* __restrict__ lrow4,
                                             int* __restrict__ cnt,
                                             int4* __restrict__ rank4,
                                             const float* __restrict__ x,
                                             const float* __restrict__ w0,
                                             const float* __restrict__ b0,
                                             float* __restrict__ h,
                                             const float* __restrict__ W,
                                             ushort* __restrict__ Bt,
                                             const float* __restrict__ W1,
                                             ushort* __restrict__ W1f) {
  int bid = blockIdx.x;
  int tid = threadIdx.x;
  if (bid < 1250) {
    int k4 = bid * 256 + tid;           // < 320000 exactly
    int4 r = lrow4[k4];
    int4 rk;
    rk.x = atomicAdd(&cnt[r.x], 1);
    rk.y = atomicAdd(&cnt[r.y], 1);
    rk.z = atomicAdd(&cnt[r.z], 1);
    rk.w = atomicAdd(&cnt[r.w], 1);
    rank4[k4] = rk;
  } else if (bid < 6250) {
    int node = (bid - 1250) * 4 + (tid >> 6);
    int j = tid & 63;
    const float* xr = x + (size_t)node * IN_FEAT;
    float acc = b0[j];
    #pragma unroll
    for (int k = 0; k < IN_FEAT; k++) acc = fmaf(xr[k], w0[k * HIDDEN + j], acc);
    h[(size_t)node * HIDDEN + j] = fmaxf(acc, 0.f);
  } else if (bid < 6762) {
    // Bt[l][c][k] = bf16(beta*W[l][k][c] + (k==c)*(1-beta))
    int gid = (bid - 6250) * 256 + tid;  // < 131072 exactly
    int l = gid >> 14;
    int rem = gid & 16383;
    int k = rem >> 7, c = rem & 127;
    float beta = logf(0.5f / (float)(l + 1) + 1.0f);
    float v = beta * W[gid];
    if (k == c) v += 1.0f - beta;
    Bt[(l << 14) + (c << 7) + k] = f2bf(v);
  } else {
    int gid = (bid - 6762) * 256 + tid;
    if (gid < FEAT * OUT_FEAT) {
      int k = gid >> 4, c = gid & 15;
      W1f[c * FEAT + k] = f2bf(W1[gid]);
    }
  }
}

// ================= K2: build_e(->x0 only) | deg-count | scanA =================
// blocks [0,20000): x0[i]=[h[src]||h[dst]] ; [20000,21250): deg histogram ;
// [21250,21407): scanA (row length = cnt+1 for self-loop)
__global__ __launch_bounds__(256) void k_mid(const int* __restrict__ src,
                                             const int* __restrict__ dst,
                                             const float* __restrict__ h,
                                             ushort* __restrict__ x0,
                                             const int4* __restrict__ lcol4,
                                             int* __restrict__ deg,
                                             const int* __restrict__ cnt,
                                             int* __restrict__ rp_out,
                                             int* __restrict__ bsum) {
  int bid = blockIdx.x;
  int tid = threadIdx.x;
  if (bid < 20000) {
    int gid = bid * 256 + tid;
    int edge = gid >> 5;
    int p = gid & 31;
    int n = (p < 16) ? src[edge] : dst[edge];
    float4 v = ((const float4*)(h + (size_t)n * HIDDEN))[p & 15];
    uint2 pk;
    pk.x = pack2(v.x, v.y);
    pk.y = pack2(v.z, v.w);
    ((uint2*)(x0 + ((size_t)edge << 7)))[p] = pk;
  } else if (bid < 21250) {
    int k4 = (bid - 20000) * 256 + tid;  // < 320000 exactly
    int4 c = lcol4[k4];
    atomicAdd(&deg[c.x], 1); atomicAdd(&deg[c.y], 1);
    atomicAdd(&deg[c.z], 1); atomicAdd(&deg[c.w], 1);
  } else {
    // scanA over (cnt+1)
    __shared__ int sh[256];
    int sb = bid - 21250;
    int base = sb * 1024 + tid * 4;
    int v[4];
    #pragma unroll
    for (int i = 0; i < 4; i++) v[i] = (base + i < N_EDGES) ? cnt[base + i] + 1 : 0;
    int t = v[0] + v[1] + v[2] + v[3];
    sh[tid] = t;
    __syncthreads();
    for (int off = 1; off < 256; off <<= 1) {
      int xv = (tid >= off) ? sh[tid - off] : 0;
      __syncthreads();
      sh[tid] += xv;
      __syncthreads();
    }
    int run = sh[tid] - t;
    #pragma unroll
    for (int i = 0; i < 4; i++) {
      if (base + i < N_EDGES) rp_out[base + i] = run;
      run += v[i];
    }
    if (tid == 255) bsum[sb] = sh[255];
  }
}

__global__ void k_scanB(int* __restrict__ bsum, int nb) {
  __shared__ int sh[256];
  int tid = threadIdx.x;
  int v = (tid < nb) ? bsum[tid] : 0;
  sh[tid] = v;
  __syncthreads();
  for (int off = 1; off < 256; off <<= 1) {
    int xv = (tid >= off) ? sh[tid - off] : 0;
    __syncthreads();
    sh[tid] += xv;
    __syncthreads();
  }
  if (tid < nb) bsum[tid] = sh[tid] - v;  // exclusive
}

// ================= K4: scanC | dis =================
// blocks [0,157): row_ptr += bsum ; [157,782): dis = rsqrt(deg+1)
__global__ __launch_bounds__(256) void k_scanC(int* __restrict__ row_ptr,
                                               const int* __restrict__ bsum,
                                               const int* __restrict__ deg,
                                               float* __restrict__ dis) {
  int bid = blockIdx.x;
  int tid = threadIdx.x;
  if (bid < 157) {
    int base = bid * 1024 + tid * 4;
    int add = bsum[bid];
    #pragma unroll
    for (int i = 0; i < 4; i++)
      if (base + i < N_EDGES) row_ptr[base + i] += add;
    if (bid == 0 && tid == 0) row_ptr[N_EDGES] = N_TOTE;
  } else {
    int i = (bid - 157) * 256 + tid;
    if (i < N_EDGES) dis[i] = rsqrtf((float)(deg[i] + 1));  // +1 self-loop
  }
}

// ================= K5: fill (NO atomics; uses rank) =================
// blocks [0,5000): real edges: pv[row_ptr[r]+rank[k]] = {c, 0.9*dis[r]*dis[c]}
// blocks [5000,5625): self-loops: pv[row_ptr[r+1]-1] = {r, 0.9*dis[r]^2}
__global__ __launch_bounds__(256) void k_fill(const int* __restrict__ lrow,
                                              const int* __restrict__ lcol,
                                              const int* __restrict__ rank,
                                              const int* __restrict__ row_ptr,
                                              const float* __restrict__ dis,
                                              uint2* __restrict__ pv) {
  int bid = blockIdx.x;
  int tid = threadIdx.x;
  if (bid < 5000) {
    int k = bid * 256 + tid;             // < 1280000 exactly
    int r = lrow[k], c = lcol[k];
    int pos = row_ptr[r] + rank[k];
    uint2 out;
    out.x = (uint)c;
    out.y = __float_as_uint((1.f - ALPHA) * dis[r] * dis[c]);
    pv[pos] = out;
  } else {
    int r = (bid - 5000) * 256 + tid;    // < 160000 exactly
    int pos = row_ptr[r + 1] - 1;
    float d = dis[r];
    uint2 out;
    out.x = (uint)r;
    out.y = __float_as_uint((1.f - ALPHA) * d * d);
    pv[pos] = out;
  }
}

// ---------------- gather phase: segmented stream + alpha*x0 folded at flush ----
__device__ __forceinline__ void gather_phase(const int* __restrict__ row_ptr,
                                             const uint2* __restrict__ pv,
                                             const uint* __restrict__ eu,
                                             const uint* __restrict__ x0u,
                                             ushort* As, int row0, int wv, int lane) {
  int r0w = row0 + wv * 16;
  int rpidx = r0w + lane;
  if (rpidx > N_EDGES) rpidx = N_EDGES;
  int myrp = row_ptr[rpidx];

  int t    = __builtin_amdgcn_readlane(myrp, 0);
  int tend = __builtin_amdgcn_readlane(myrp, 16);
  int r    = r0w;
  int end  = __builtin_amdgcn_readlane(myrp, 1);

  float ax = 0.f, ay = 0.f;
  uint uA[CHUNK], uB[CHUNK];
  uint2 P, Pn;
  uint xq = x0u[((size_t)r0w << 6) + lane];   // x0 row prefetch

  auto loadpv16 = [&](int tb_, uint2& p) {
    p = pv[tb_ + (lane & 15)];            // 128B line, covers 2 chunks
  };
  auto gather8 = [&](int tb_, const uint2& p, int base, uint* uu) {
    #pragma unroll
    for (int j = 0; j < CHUNK; j++) {
      int cu = (tb_ + j < tend)
                 ? __builtin_amdgcn_readlane((int)p.x, base + j)
                 : 0;
      uu[j] = eu[((size_t)cu << 6) + lane];
    }
  };
  auto flush = [&]() {
    int rl = r - row0;
    float2 fx = bf2(xq);
    *(uint*)((char*)As + rl * 256 + ((lane * 4) ^ ((rl & 7) << 4))) =
        pack2(fmaf(ALPHA, fx.x, ax), fmaf(ALPHA, fx.y, ay));
    ax = 0.f; ay = 0.f;
    if (r + 1 < r0w + 16) xq = x0u[((size_t)(r + 1) << 6) + lane];  // next row
  };
  auto consume8 = [&](int tb_, const uint2& p, int base, const uint* uu) {
    #pragma unroll
    for (int j = 0; j < CHUNK; j++) {
      int tj = tb_ + j;
      if (tj < tend) {                      // wave-uniform
        while (tj >= end) {                 // row boundary (wave-uniform)
          flush();
          r++;
          end = __builtin_amdgcn_readlane(myrp, r - r0w + 1);
        }
        float v = __uint_as_float(__builtin_amdgcn_readlane((int)p.y, base + j));
        float2 f = bf2(uu[j]);
        ax = fmaf(v, f.x, ax);
        ay = fmaf(v, f.y, ay);
      }
    }
  };

  int tb = t;
  loadpv16(tb, P);
  gather8(tb, P, 0, uA);
  while (true) {
    loadpv16(tb + 16, Pn);                  // pv for chunks +2,+3
    gather8(tb + CHUNK, P, 8, uB);
    consume8(tb, P, 0, uA);
    tb += CHUNK;
    if (tb >= tend) break;
    gather8(tb + CHUNK, Pn, 0, uA);
    consume8(tb, P, 8, uB);
    tb += CHUNK;
    if (tb >= tend) break;
    P = Pn;
  }
  flush();  // last row (every row has >=1 edge via self-loop)
}

// ---------------- MFMA accumulate: acc = As@W' ----------------
__device__ __forceinline__ void mfma_accum(const ushort* As,
                                           const ushort* __restrict__ Bt,
                                           int wv, int l15, int l4,
                                           f32x4 acc[4][2]) {
  const char* btA = (const char*)Bt + (size_t)(wv * 32 + l15) * 256;
  const char* btB = btA + 16 * 256;
  #pragma unroll
  for (int kb = 0; kb < 4; kb++) {
    int kbyte = kb * 64 + l4 * 16;
    bf16x8 b0 = *(const bf16x8*)(btA + kbyte);
    bf16x8 b1 = *(const bf16x8*)(btB + kbyte);
    #pragma unroll
    for (int mr = 0; mr < 4; mr++) {
      int rr = mr * 16 + l15;
      bf16x8 afr = *(const bf16x8*)((const char*)As + rr * 256 + (kbyte ^ ((rr & 7) << 4)));
      acc[mr][0] = __builtin_amdgcn_mfma_f32_16x16x32_bf16(afr, b0, acc[mr][0], 0, 0, 0);
      acc[mr][1] = __builtin_amdgcn_mfma_f32_16x16x32_bf16(afr, b1, acc[mr][1], 0, 0, 0);
    }
  }
}

// ---------------- fused layer (layers 0..6): -> e_out bf16 ----------------
__global__ __launch_bounds__(256, 6) void k_layer(const int* __restrict__ row_ptr,
                                                  const uint2* __restrict__ pv,
                                                  const ushort* __restrict__ e_in,
                                                  const ushort* __restrict__ x0,
                                                  const ushort* __restrict__ Bt,
                                                  ushort* __restrict__ e_out) {
  __shared__ __align__(16) ushort As[64 * 128];  // 16KB
  int tid = threadIdx.x;
  int wv = tid >> 6, lane = tid & 63;
  int l15 = lane & 15, l4 = lane >> 4;
  int row0 = blockIdx.x * 64;

  gather_phase(row_ptr, pv, (const uint*)e_in, (const uint*)x0, As, row0, wv, lane);
  __syncthreads();

  f32x4 acc[4][2];
  #pragma unroll
  for (int i = 0; i < 4; i++) { acc[i][0] = (f32x4)0; acc[i][1] = (f32x4)0; }
  mfma_accum(As, Bt, wv, l15, l4, acc);

  __syncthreads();  // all waves done reading As
  // stage relu(acc) into As as [row][col] bf16 (XOR bits 4-6 per row)
  #pragma unroll
  for (int mr = 0; mr < 4; mr++) {
    #pragma unroll
    for (int n = 0; n < 2; n++) {
      int col = wv * 32 + n * 16 + l15;
      #pragma unroll
      for (int j = 0; j < 4; j++) {
        int rl = mr * 16 + l4 * 4 + j;
        float v = fmaxf(acc[mr][n][j], 0.f);
        *(ushort*)((char*)As + rl * 256 + ((col * 2) ^ ((rl & 7) << 4))) = f2bf(v);
      }
    }
  }
  __syncthreads();
  // full-line coalesced copy-out: 1024 16B chunks
  const char* asb = (const char*)As;
  #pragma unroll
  for (int k2 = 0; k2 < 4; k2++) {
    int q = k2 * 256 + tid;
    int rl = q >> 4, ck = q & 15;
    uint4 v = *(const uint4*)(asb + rl * 256 + ((ck * 16) ^ ((rl & 7) << 4)));
    *(uint4*)((char*)e_out + (((size_t)(row0 + rl)) << 8) + ck * 16) = v;
  }
}

// ---------------- last layer: fused lin1, writes out fp32 ----------------
__global__ __launch_bounds__(256, 4) void k_layer_last(const int* __restrict__ row_ptr,
                                                       const uint2* __restrict__ pv,
                                                       const ushort* __restrict__ e_in,
                                                       const ushort* __restrict__ x0,
                                                       const ushort* __restrict__ Bt,
                                                       const ushort* __restrict__ W1f,
                                                       const float* __restrict__ b1,
                                                       float* __restrict__ out) {
  __shared__ __align__(16) ushort As[64 * 128];  // 16KB
  int tid = threadIdx.x;
  int wv = tid >> 6, lane = tid & 63;
  int l15 = lane & 15, l4 = lane >> 4;
  int row0 = blockIdx.x * 64;

  gather_phase(row_ptr, pv, (const uint*)e_in, (const uint*)x0, As, row0, wv, lane);
  __syncthreads();

  f32x4 acc[4][2];
  #pragma unroll
  for (int i = 0; i < 4; i++) { acc[i][0] = (f32x4)0; acc[i][1] = (f32x4)0; }
  mfma_accum(As, Bt, wv, l15, l4, acc);

  __syncthreads();  // all waves done reading As
  // relu -> bf16 e-tile back into As (swizzled)
  #pragma unroll
  for (int mr = 0; mr < 4; mr++) {
    #pragma unroll
    for (int n = 0; n < 2; n++) {
      int col = wv * 32 + n * 16 + l15;
      #pragma unroll
      for (int j = 0; j < 4; j++) {
        int rl = mr * 16 + l4 * 4 + j;
        float v = fmaxf(acc[mr][n][j], 0.f);
        *(ushort*)((char*)As + rl * 256 + ((col * 2) ^ ((rl & 7) << 4))) = f2bf(v);
      }
    }
  }
  __syncthreads();

  // lin1: out(64x16) = e_tile(64x128) @ W1(128x16) + b1
  f32x4 acc2[4];
  #pragma unroll
  for (int i = 0; i < 4; i++) acc2[i] = (f32x4)0;
  const char* w1p = (const char*)W1f + (size_t)l15 * 256;
  #pragma unroll
  for (int kb = 0; kb < 4; kb++) {
    int kbyte = kb * 64 + l4 * 16;
    bf16x8 wfr = *(const bf16x8*)(w1p + kbyte);
    #pragma unroll
    for (int mr = 0; mr < 4; mr++) {
      int rr = mr * 16 + l15;
      bf16x8 afr = *(const bf16x8*)((const char*)As + rr * 256 + (kbyte ^ ((rr & 7) << 4)));
      acc2[mr] = __builtin_amdgcn_mfma_f32_16x16x32_bf16(afr, wfr, acc2[mr], 0, 0, 0);
    }
  }
  float bias = b1[l15];
  #pragma unroll
  for (int mr = 0; mr < 4; mr++) {
    int rowb = row0 + mr * 16 + l4 * 4;
    #pragma unroll
    for (int j = 0; j < 4; j++)
      out[(size_t)(rowb + j) * OUT_FEAT + l15] = acc2[mr][j] + bias;
  }
}

extern "C" void kernel_launch(void* const* d_in, const int* in_sizes, int n_in,
                              void* d_out, int out_size, void* d_ws, size_t ws_size,
                              hipStream_t stream) {
  const float* x   = (const float*)d_in[0];
  const int*   ei  = (const int*)d_in[1];
  const int*   lei = (const int*)d_in[2];
  const float* w0  = (const float*)d_in[3];
  const float* b0  = (const float*)d_in[4];
  const float* cw  = (const float*)d_in[5];
  const float* w1  = (const float*)d_in[6];
  const float* b1  = (const float*)d_in[7];
  float* out = (float*)d_out;

  char* ws = (char*)d_ws;
  size_t off = 0;
  auto alloc = [&](size_t bytes) -> void* {
    void* p = ws + off;
    off += (bytes + 255) & ~(size_t)255;
    return p;
  };
  float*  h      = (float*)alloc((size_t)N_NODES * HIDDEN * 4);
  ushort* x0m    = (ushort*)alloc((size_t)N_EDGES * FEAT * 2);
  ushort* eB     = (ushort*)alloc((size_t)N_EDGES * FEAT * 2);
  ushort* eC     = (ushort*)alloc((size_t)N_EDGES * FEAT * 2);
  ushort* Btp    = (ushort*)alloc((size_t)NUM_LAYERS * FEAT * FEAT * 2);
  ushort* W1f    = (ushort*)alloc((size_t)FEAT * OUT_FEAT * 2);
  int*    deg    = (int*)alloc((size_t)N_EDGES * 4);
  float*  dis    = (float*)alloc((size_t)N_EDGES * 4);
  int*    cnt    = (int*)alloc((size_t)N_EDGES * 4);
  int*    rank   = (int*)alloc((size_t)N_LEDGES * 4);
  int*    row_ptr= (int*)alloc((size_t)(N_EDGES + 1) * 4);
  uint2*  pv     = (uint2*)alloc(((size_t)N_TOTE + 32) * 8);  // +pad for unguarded loads
  int*    bsum   = (int*)alloc(256 * 4);

  hipMemsetAsync(cnt, 0, (size_t)N_EDGES * 4, stream);
  hipMemsetAsync(deg, 0, (size_t)N_EDGES * 4, stream);

  // K1: cnt-count(+rank) | lin0 | prepw | prepw1
  k_pre<<<6770, 256, 0, stream>>>((const int4*)lei, cnt, (int4*)rank,
                                  x, w0, b0, h, cw, Btp, w1, W1f);
  // K2: build_e(->x0) | deg-count | scanA
  k_mid<<<21407, 256, 0, stream>>>(ei, ei + N_EDGES, h, x0m,
                                   (const int4*)(lei + N_LEDGES), deg,
                                   cnt, row_ptr, bsum);
  k_scanB<<<1, 256, 0, stream>>>(bsum, 157);
  // K4: scanC | dis
  k_scanC<<<782, 256, 0, stream>>>(row_ptr, bsum, deg, dis);
  // K5: fill, no atomics
  k_fill<<<5625, 256, 0, stream>>>(lei, lei + N_LEDGES, rank, row_ptr, dis, pv);

  ushort* bufs[2] = { eB, eC };
  ushort* ein = x0m;
  for (int l = 0; l < NUM_LAYERS - 1; l++) {
    k_layer<<<N_EDGES / 64, 256, 0, stream>>>(row_ptr, pv, ein, x0m,
                                              Btp + ((size_t)l << 14), bufs[l & 1]);
    ein = bufs[l & 1];
  }
  k_layer_last<<<N_EDGES / 64, 256, 0, stream>>>(row_ptr, pv, ein, x0m,
                                                 Btp + ((size_t)(NUM_LAYERS - 1) << 14),
                                                 W1f, b1, out);
}